// Round 12
// baseline (548.373 us; speedup 1.0000x reference)
//
#include <hip/hip_runtime.h>
#include <math.h>

typedef _Float16 half8 __attribute__((ext_vector_type(8)));
typedef _Float16 half4v __attribute__((ext_vector_type(4)));
typedef float f32x4 __attribute__((ext_vector_type(4)));

#define LOG2E 1.44269504f

// ---------------- merged weight-pack kernel (all 5 packs, r2-verified layouts) -------------
__device__ __forceinline__ void pack_generic(int rem, int NT, int COUT, float scale,
                                             const float* __restrict__ src,
                                             _Float16* __restrict__ dst) {
  int j = rem & 7, lane = (rem >> 3) & 63, rest = rem >> 9;
  int t = rest % NT, s = rest / NT;
  int oc = t * 16 + (lane & 15);
  int tap = s >> 1;
  int ic = (s & 1) * 32 + ((lane >> 4) & 3) * 8 + j;
  float v = (oc < COUT) ? src[((size_t)oc * 64 + ic) * 9 + tap] * scale : 0.f;
  dst[rem] = (_Float16)v;
}

__global__ void pack_all_kernel(const float* __restrict__ fWa, const float* __restrict__ fWb,
                                const float* __restrict__ fWc, const float* __restrict__ W2a,
                                const float* __restrict__ W2b,
                                _Float16* __restrict__ Bp1, _Float16* __restrict__ BpA,
                                _Float16* __restrict__ BpB, _Float16* __restrict__ Bpb,
                                _Float16* __restrict__ Bpc) {
  int idx = blockIdx.x * blockDim.x + threadIdx.x;
  if (idx < 184320) {                       // Bpb: 5 scales x 18x4x512
    int sc = idx / 36864, rem = idx - sc * 36864;
    pack_generic(rem, 4, 64, 1.f, fWb + sc * 36864, Bpb + sc * 36864);
  } else if (idx < 460800) {                // Bpc: 5 scales x 18x6x512, prescaled by log2e
    int i2 = idx - 184320;
    int sc = i2 / 55296, rem = i2 - sc * 55296;
    pack_generic(rem, 6, 81, LOG2E, fWc + sc * 46656, Bpc + sc * 55296);
  } else if (idx < 471040) {                // Bp1: conv1, K=9 pad 32
    int i2 = idx - 460800;
    int sc = i2 >> 11, rem = i2 & 2047;
    int j = rem & 7, lane = (rem >> 3) & 63, nt = rem >> 9;
    int oc = nt * 16 + (lane & 15);
    int k = ((lane >> 4) & 3) * 8 + j;
    float v = (k < 9) ? fWa[sc * 576 + oc * 9 + k] : 0.f;
    Bp1[sc * 2048 + rem] = (_Float16)v;
  } else if (idx < 475136) {                // BpA: tail stage1, K=45 pad 64
    int rem = idx - 471040;
    int j = rem & 7, lane = (rem >> 3) & 63;
    int nt = (rem >> 9) & 3, s = rem >> 11;
    int oc = nt * 16 + (lane & 15);
    int k = s * 32 + ((lane >> 4) & 3) * 8 + j;
    float v = 0.f;
    if (k < 45) { int ic = k / 9, tap = k - ic * 9; v = W2a[(oc * 5 + ic) * 9 + tap]; }
    BpA[rem] = (_Float16)v;
  } else if (idx < 484352) {                // BpB: tail stage2 (COUT=1, NT=1)
    pack_generic(idx - 475136, 1, 1, 1.f, W2b, BpB);
  }
}

// ---------------- merged nearest downsample -> fp16 (s1,s2,s3 both batches) ----------------
__global__ void down_all_kernel(const float* __restrict__ x, _Float16* __restrict__ s1,
                                _Float16* __restrict__ s2, _Float16* __restrict__ s3) {
  int idx = blockIdx.x * blockDim.x + threadIdx.x;
  if (idx < 131072) {
    int n = idx >> 16, p = idx & 65535, rr = p >> 8, cc = p & 255;
    s1[idx] = (_Float16)x[(size_t)n * 262144 + (size_t)(rr * 2) * 512 + cc * 2];
  } else if (idx < 163840) {
    int i2 = idx - 131072;
    int n = i2 >> 14, p = i2 & 16383, rr = p >> 7, cc = p & 127;
    s2[i2] = (_Float16)x[(size_t)n * 262144 + (size_t)(rr * 4) * 512 + cc * 4];
  } else if (idx < 172032) {
    int i2 = idx - 163840;
    int n = i2 >> 12, p = i2 & 4095, rr = p >> 6, cc = p & 63;
    s3[i2] = (_Float16)x[(size_t)n * 262144 + (size_t)(rr * 8) * 512 + cc * 8];
  }
}

// ---------------- block -> (scale, batch, tile) mapping, all 5 scales in one grid ----------
__device__ __forceinline__ void map_block(int bid, int& sc, int& n, int& bx, int& by,
                                          int& Hs, int& RS, int& h2off) {
  if (bid < 2048) { sc = 0; Hs = 512; RS = 1; h2off = 0;
    int t = bid; n = t >> 10; t &= 1023; by = t >> 5; bx = t & 31; }
  else if (bid < 4096) { sc = 4; Hs = 512; RS = 1; h2off = 33554432;
    int t = bid - 2048; n = t >> 10; t &= 1023; by = t >> 5; bx = t & 31; }
  else if (bid < 4608) { sc = 1; Hs = 256; RS = 2; h2off = 67108864;
    int t = bid - 4096; n = t >> 8; t &= 255; by = t >> 4; bx = t & 15; }
  else if (bid < 4736) { sc = 2; Hs = 128; RS = 4; h2off = 75497472;
    int t = bid - 4608; n = t >> 6; t &= 63; by = t >> 3; bx = t & 7; }
  else { sc = 3; Hs = 64; RS = 8; h2off = 77594624;
    int t = bid - 4736; n = t >> 4; t &= 15; by = t >> 2; bx = t & 3; }
}

__device__ __forceinline__ const void* pick_src(int sc, const float* x, const float* g,
                                                const _Float16* s1, const _Float16* s2,
                                                const _Float16* s3, int& sStr, bool& f16s) {
  if (sc == 0) { sStr = 262144; f16s = false; return x; }
  if (sc == 1) { sStr = 65536; f16s = true; return s1; }
  if (sc == 2) { sStr = 16384; f16s = true; return s2; }
  if (sc == 3) { sStr = 4096; f16s = true; return s3; }
  sStr = 262144; f16s = false; return g;
}

__device__ __forceinline__ float src_load(const void* p, bool f16s, size_t off) {
  return f16s ? (float)((const _Float16*)p)[off] : ((const float*)p)[off];
}

// ---------------- shared MFMA K-loop over 18x18x64 XOR-swizzled slab (r2-verified) ---------
// Used by tail stage 2 only now.
template <int NT, bool SWAP>
__device__ __forceinline__ void mfma_acc18(const _Float16* slab, const half8* __restrict__ Bp,
                                           f32x4 (&acc)[4][NT], int tid) {
  const int lane = tid & 63;
  const int wv = tid >> 6;
  const int quad = lane >> 4;
  const int ln15 = lane & 15;
  const f32x4 zz = {0.f, 0.f, 0.f, 0.f};
#pragma unroll
  for (int mt = 0; mt < 4; ++mt)
#pragma unroll
    for (int nt = 0; nt < NT; ++nt) acc[mt][nt] = zz;
#pragma unroll 1
  for (int s = 0; s < 18; ++s) {
    const int tap = s >> 1;
    const int dy = tap / 3;
    const int dx = tap - dy * 3;
    half8 bf[NT];
#pragma unroll
    for (int nt = 0; nt < NT; ++nt) bf[nt] = Bp[(s * NT + nt) * 64 + lane];
    const int C = dx + ln15;
    const int qsw = (((s & 1) * 4 + quad) ^ (C & 7));
    const _Float16* base = slab + C * 64 + qsw * 8;
    half8 af[4];
#pragma unroll
    for (int mt = 0; mt < 4; ++mt) {
      const int R = wv * 4 + mt + dy;
      af[mt] = *(const half8*)(base + R * (18 * 64));
    }
#pragma unroll
    for (int mt = 0; mt < 4; ++mt)
#pragma unroll
      for (int nt = 0; nt < NT; ++nt)
        acc[mt][nt] = SWAP
          ? __builtin_amdgcn_mfma_f32_16x16x32_f16(bf[nt], af[mt], acc[mt][nt], 0, 0, 0)
          : __builtin_amdgcn_mfma_f32_16x16x32_f16(af[mt], bf[nt], acc[mt][nt], 0, 0, 0);
  }
}

template <int NT, int COUT, int COUTP, bool RELU, typename OutT>
__device__ __forceinline__ void mfma_body(const _Float16* slab, const half8* __restrict__ Bp,
                                          const float* __restrict__ bias,
                                          OutT* __restrict__ out,
                                          int H, int W, int gr0, int gc0, int tid) {
  f32x4 acc[4][NT];
  mfma_acc18<NT, false>(slab, Bp, acc, tid);
  const int lane = tid & 63;
  const int wv = tid >> 6;
  const int quad = lane >> 4;
  const int ln15 = lane & 15;
  float bvv[NT];
#pragma unroll
  for (int nt = 0; nt < NT; ++nt) {
    const int oc = nt * 16 + ln15;
    bvv[nt] = (oc < COUT) ? bias[oc] : 0.f;
  }
#pragma unroll
  for (int mt = 0; mt < 4; ++mt) {
    const int gr = gr0 + wv * 4 + mt;
#pragma unroll
    for (int reg = 0; reg < 4; ++reg) {
      const int gc = gc0 + quad * 4 + reg;
#pragma unroll
      for (int nt = 0; nt < NT; ++nt) {
        const int oc = nt * 16 + ln15;
        float v = acc[mt][nt][reg] + bvv[nt];
        if (RELU) v = fmaxf(v, 0.f);
        if (oc < COUTP) out[((size_t)gr * W + gc) * COUTP + oc] = (OutT)v;
      }
    }
  }
}

// ---------------- all-scale fused conv1+conv2 (MFMA), split-K halved slab ------------------
// Slab holds one 32-ic half (324 x 40 halves = 25.9 KB; total LDS 27.5 KB -> 5 blocks/CU,
// was 3). Per phase h: conv1 computes ONLY nt pair {2h, 2h+1} (no recompute) with swapped
// MFMA -> lane holds 4 consecutive ch of pixel ln15 -> unswizzled ds_write_b64 at
// p*40 + ntl*16 + quad*4 (bank-distinct per phase). conv2 runs the 9 taps s = tap*2+h
// (pack already k-ordered this way); acc2 persists across phases.
__global__ __launch_bounds__(256)
void conv12_ms_kernel(const float* __restrict__ x, const float* __restrict__ g,
                      const _Float16* __restrict__ s1, const _Float16* __restrict__ s2,
                      const _Float16* __restrict__ s3,
                      const half8* __restrict__ Bp1b, const float* __restrict__ fba,
                      const half8* __restrict__ Bpbb, const float* __restrict__ fbb,
                      _Float16* __restrict__ h2) {
  __shared__ float xs[20 * 20];                         // first: gather clamps stay inside
  __shared__ __align__(16) _Float16 slab[324 * 40];     // 25920 B
  int sc, n, bx, by, Hs, RS, h2off;
  map_block(blockIdx.x, sc, n, bx, by, Hs, RS, h2off);
  int sStr; bool f16s;
  const void* src = pick_src(sc, x, g, s1, s2, s3, sStr, f16s);
  _Float16* out = h2 + h2off + (size_t)n * Hs * Hs * 64;
  const half8* Bp1 = Bp1b + sc * 256;
  const half8* Bp = Bpbb + sc * 4608;
  const float* ba = fba + sc * 64;
  const float* bb = fbb + sc * 64;
  const int H = Hs, W = Hs;
  const int tid = threadIdx.x;
  const int gr0 = by * 16, gc0 = bx * 16;
  for (int i = tid; i < 400; i += 256) {
    int R = i / 20, C = i % 20;
    int gr = gr0 - 2 + R, gc = gc0 - 2 + C;
    xs[i] = (gr >= 0 && gr < H && gc >= 0 && gc < W)
                ? src_load(src, f16s, (size_t)n * sStr + (size_t)gr * W + gc) : 0.f;
  }
  __syncthreads();
  const int lane = tid & 63;
  const int wv = tid >> 6;
  const int quad = lane >> 4;
  const int ln15 = lane & 15;
  half8 bf1[4];
  float b1v[4][4];
#pragma unroll
  for (int nt = 0; nt < 4; ++nt) {
    bf1[nt] = Bp1[nt * 64 + lane];
#pragma unroll
    for (int reg = 0; reg < 4; ++reg) b1v[nt][reg] = ba[nt * 16 + quad * 4 + reg];
  }
  int off1[8];
  bool v1[8];
#pragma unroll
  for (int j = 0; j < 8; ++j) {
    int k = quad * 8 + j;
    v1[j] = (k < 9);
    off1[j] = v1[j] ? ((k / 3) * 20 + (k % 3)) : 0;
  }
  const f32x4 zz = {0.f, 0.f, 0.f, 0.f};
  f32x4 acc2[4][4];
#pragma unroll
  for (int mt = 0; mt < 4; ++mt)
#pragma unroll
    for (int nt = 0; nt < 4; ++nt) acc2[mt][nt] = zz;
#pragma unroll 1
  for (int h = 0; h < 2; ++h) {
    if (h) __syncthreads();                              // phase-0 readers done
    // conv1 for ch-half h (nt = 2h, 2h+1); swapped-D; store to slab half
#pragma unroll 1
    for (int mt = wv; mt < 21; mt += 4) {
      int p = mt * 16 + ln15;
      int pcl = (p < 323) ? p : 323;
      int Rg = pcl / 18, Cg = pcl - Rg * 18;
      int base = Rg * 20 + Cg;
      half8 af;
#pragma unroll
      for (int j = 0; j < 8; ++j)
        af[j] = v1[j] ? (_Float16)xs[base + off1[j]] : (_Float16)0.f;
      f32x4 a1[2] = {zz, zz};
#pragma unroll
      for (int ntl = 0; ntl < 2; ++ntl)
        a1[ntl] = __builtin_amdgcn_mfma_f32_16x16x32_f16(bf1[2 * h + ntl], af, a1[ntl], 0, 0, 0);
      if (p < 324) {
        int R2 = p / 18, C2 = p - R2 * 18;
        int gr = gr0 - 1 + R2, gc = gc0 - 1 + C2;
        bool inb = (gr >= 0 && gr < H && gc >= 0 && gc < W);
#pragma unroll
        for (int ntl = 0; ntl < 2; ++ntl) {
          half4v w;
#pragma unroll
          for (int reg = 0; reg < 4; ++reg) {
            float v = inb ? fmaxf(a1[ntl][reg] + b1v[2 * h + ntl][reg], 0.f) : 0.f;
            w[reg] = (_Float16)v;
          }
          *(half4v*)(slab + p * 40 + ntl * 16 + quad * 4) = w;
        }
      }
    }
    __syncthreads();
    // conv2 K-half: 9 taps, s = tap*2 + h; unswapped (D px x ch for h2 store)
#pragma unroll 1
    for (int tap = 0; tap < 9; ++tap) {
      const int dy = tap / 3;
      const int dx = tap - dy * 3;
      const int s = tap * 2 + h;
      half8 bf[4];
#pragma unroll
      for (int nt = 0; nt < 4; ++nt) bf[nt] = Bp[(s * 4 + nt) * 64 + lane];
      const int C = dx + ln15;
      const _Float16* baseA = slab + C * 40 + quad * 8;
      half8 af2[4];
#pragma unroll
      for (int mt = 0; mt < 4; ++mt)
        af2[mt] = *(const half8*)(baseA + (wv * 4 + mt + dy) * 720);  // 18*40
#pragma unroll
      for (int mt = 0; mt < 4; ++mt)
#pragma unroll
        for (int nt = 0; nt < 4; ++nt)
          acc2[mt][nt] = __builtin_amdgcn_mfma_f32_16x16x32_f16(af2[mt], bf[nt], acc2[mt][nt], 0, 0, 0);
    }
  }
  // h2 store epilogue (px-major for write combining)
  float bvv[4];
#pragma unroll
  for (int nt = 0; nt < 4; ++nt) bvv[nt] = bb[nt * 16 + ln15];
#pragma unroll
  for (int mt = 0; mt < 4; ++mt) {
    const int gr = gr0 + wv * 4 + mt;
#pragma unroll
    for (int reg = 0; reg < 4; ++reg) {
      const int gc = gc0 + quad * 4 + reg;
#pragma unroll
      for (int nt = 0; nt < 4; ++nt) {
        const int oc = nt * 16 + ln15;
        out[((size_t)gr * W + gc) * 64 + oc] = (_Float16)fmaxf(acc2[mt][nt][reg] + bvv[nt], 0.f);
      }
    }
  }
}

// ---------------- all-scale fused conv3 + softmax + dynconv + upsample (r10-proven) --------
// Split-K restage, stride-40 slab (25.9 KB); swapped MFMA epilogue; planar cat.
__global__ __launch_bounds__(256)
void conv3sd_ms_kernel(const _Float16* __restrict__ h2, const half8* __restrict__ Bpcb,
                       const float* __restrict__ fbc,
                       const float* __restrict__ x, const float* __restrict__ g,
                       const _Float16* __restrict__ s1, const _Float16* __restrict__ s2,
                       const _Float16* __restrict__ s3, float* __restrict__ cat) {
  __shared__ __align__(16) _Float16 slab[324 * 40];     // 25920 B
  __shared__ float xs[24 * 24];
  int sc, n, bx, by, Hs, RS, h2off;
  map_block(blockIdx.x, sc, n, bx, by, Hs, RS, h2off);
  int sStr; bool f16s;
  const void* src = pick_src(sc, x, g, s1, s2, s3, sStr, f16s);
  const _Float16* in = h2 + h2off + (size_t)n * Hs * Hs * 64;
  const half8* Bp = Bpcb + sc * 6912;
  const float* bias = fbc + sc * 81;
  float* catp = cat + (size_t)(sc * 2 + n) * 262144;
  const int H = Hs, W = Hs;
  const int tid = threadIdx.x;
  const int gr0 = by * 16, gc0 = bx * 16;
  const int lane = tid & 63;
  const int wv = tid >> 6;
  const int quad = lane >> 4;
  const int ln15 = lane & 15;
  for (int i = tid; i < 576; i += 256) {
    int R = i / 24, C = i % 24;
    int gr = gr0 - 4 + R, gc = gc0 - 4 + C;
    xs[i] = (gr >= 0 && gr < H && gc >= 0 && gc < W)
                ? src_load(src, f16s, (size_t)n * sStr + (size_t)gr * W + gc) : 0.f;
  }
  f32x4 acc[4][6];
  const f32x4 zz = {0.f, 0.f, 0.f, 0.f};
#pragma unroll
  for (int mt = 0; mt < 4; ++mt)
#pragma unroll
    for (int nt = 0; nt < 6; ++nt) acc[mt][nt] = zz;
#pragma unroll 1
  for (int h = 0; h < 2; ++h) {
    if (h) __syncthreads();                              // phase-A readers done
    for (int i = tid; i < 1296; i += 256) {              // 18*18 px x 4 chunks
      int chunk = i & 3, px = i >> 2;
      int R = px / 18, C = px - R * 18;
      int gr = gr0 - 1 + R, gc = gc0 - 1 + C;
      half8 v = {0, 0, 0, 0, 0, 0, 0, 0};
      if (gr >= 0 && gr < H && gc >= 0 && gc < W)
        v = *(const half8*)(in + ((size_t)gr * W + gc) * 64 + (h * 4 + chunk) * 8);
      *(half8*)(slab + px * 40 + chunk * 8) = v;
    }
    __syncthreads();
#pragma unroll 1
    for (int tap = 0; tap < 9; ++tap) {
      const int dy = tap / 3;
      const int dx = tap - dy * 3;
      half8 bf[6];
#pragma unroll
      for (int nt = 0; nt < 6; ++nt) bf[nt] = Bp[(((tap * 2 + h) * 6) + nt) * 64 + lane];
      const int C = dx + ln15;
      const _Float16* base = slab + C * 40 + quad * 8;
      half8 af[4];
#pragma unroll
      for (int mt = 0; mt < 4; ++mt) {
        const int R = wv * 4 + mt + dy;
        af[mt] = *(const half8*)(base + R * 720);        // 18*40
      }
#pragma unroll
      for (int mt = 0; mt < 4; ++mt)
#pragma unroll
        for (int nt = 0; nt < 6; ++nt)
          acc[mt][nt] = __builtin_amdgcn_mfma_f32_16x16x32_f16(bf[nt], af[mt], acc[mt][nt], 0, 0, 0);
    }
  }
  float bvv[6][4];
  int dyx[6][4];
  bool vv[6][4];
#pragma unroll
  for (int nt = 0; nt < 6; ++nt)
#pragma unroll
    for (int reg = 0; reg < 4; ++reg) {
      int ch = nt * 16 + quad * 4 + reg;
      bool ok = (ch < 81);
      vv[nt][reg] = ok;
      bvv[nt][reg] = ok ? bias[ch] * LOG2E : 0.f;
      int dy = ch / 9, dx = ch - dy * 9;
      dyx[nt][reg] = ok ? dy * 24 + dx : 0;
    }
  const int lrs = (RS == 2) ? 1 : ((RS == 4) ? 2 : 3);
#pragma unroll
  for (int mt = 0; mt < 4; ++mt) {
    const float* xb = xs + (wv * 4 + mt) * 24 + ln15;
    float sum = 0.f, y = 0.f;
#pragma unroll
    for (int nt = 0; nt < 6; ++nt)
#pragma unroll
      for (int reg = 0; reg < 4; ++reg) {
        if (vv[nt][reg]) {
          float e = exp2f(acc[mt][nt][reg] + bvv[nt][reg]);
          sum += e;
          y = fmaf(e, xb[dyx[nt][reg]], y);
        }
      }
    sum += __shfl_xor(sum, 16, 64);
    sum += __shfl_xor(sum, 32, 64);
    y += __shfl_xor(y, 16, 64);
    y += __shfl_xor(y, 32, 64);
    const float o = y / sum;
    const int gr = gr0 + wv * 4 + mt, gc = gc0 + ln15;
    if (RS == 1) {
      if (quad == 0) catp[(size_t)gr * 512 + gc] = o;
    } else {
      for (int t = quad; t < RS * RS; t += 4) {
        int a = t >> lrs, b = t & (RS - 1);
        catp[((size_t)(gr * RS + a)) * 512 + (gc * RS + b)] = o;
      }
    }
  }
}

// ---------------- fused tail: cat(5 planes) -> MFMA 5->64 relu (LDS) -> MFMA 64->1 ---------
__global__ __launch_bounds__(256)
void tail_fused_kernel(const float* __restrict__ cat,
                       const half8* __restrict__ BpA, const float* __restrict__ b2a,
                       const half8* __restrict__ BpB, const float* __restrict__ b2b,
                       float* __restrict__ out) {
  __shared__ float cs[20 * 20 * 5];                      // first: gather clamps stay inside
  __shared__ __align__(16) _Float16 hid[18 * 18 * 64];
  const int n = blockIdx.z;
  float* op = out + (size_t)n * (512 * 512);
  const int tid = threadIdx.x;
  const int gr0 = blockIdx.y * 16, gc0 = blockIdx.x * 16;
  for (int i = tid; i < 2000; i += 256) {
    int ic = i / 400, px = i - ic * 400;
    int R = px / 20, C = px - R * 20;
    int gr = gr0 - 2 + R, gc = gc0 - 2 + C;
    cs[px * 5 + ic] = (gr >= 0 && gr < 512 && gc >= 0 && gc < 512)
                ? cat[(size_t)(ic * 2 + n) * 262144 + (size_t)gr * 512 + gc] : 0.f;
  }
  __syncthreads();
  const int lane = tid & 63;
  const int wv = tid >> 6;
  const int quad = lane >> 4;
  const int ln15 = lane & 15;
  int goff[2][8];
  bool gok[2][8];
#pragma unroll
  for (int s = 0; s < 2; ++s)
#pragma unroll
    for (int j = 0; j < 8; ++j) {
      int k = s * 32 + quad * 8 + j;
      bool ok = (k < 45);
      int ic = k / 9;
      int tap = k - ic * 9;
      int dy = tap / 3, dx = tap - dy * 3;
      goff[s][j] = ok ? ((dy * 20 + dx) * 5 + ic) : 0;
      gok[s][j] = ok;
    }
  half8 bfA[2][4];
  float bAv[4][4];
#pragma unroll
  for (int s = 0; s < 2; ++s)
#pragma unroll
    for (int nt = 0; nt < 4; ++nt) bfA[s][nt] = BpA[(s * 4 + nt) * 64 + lane];
#pragma unroll
  for (int nt = 0; nt < 4; ++nt)
#pragma unroll
    for (int reg = 0; reg < 4; ++reg) bAv[nt][reg] = b2a[nt * 16 + quad * 4 + reg];
  const f32x4 zz = {0.f, 0.f, 0.f, 0.f};
#pragma unroll 1
  for (int mt = wv; mt < 21; mt += 4) {
    int p = mt * 16 + ln15;
    int pcl = (p < 323) ? p : 323;
    int base = (pcl / 18) * 100 + (pcl % 18) * 5;
    f32x4 acc1[4] = {zz, zz, zz, zz};
#pragma unroll
    for (int s = 0; s < 2; ++s) {
      half8 af;
#pragma unroll
      for (int j = 0; j < 8; ++j) {
        float a = gok[s][j] ? cs[base + goff[s][j]] : 0.f;
        af[j] = (_Float16)a;
      }
#pragma unroll
      for (int nt = 0; nt < 4; ++nt)
        acc1[nt] = __builtin_amdgcn_mfma_f32_16x16x32_f16(bfA[s][nt], af, acc1[nt], 0, 0, 0);
    }
    if (p < 324) {
      int R2 = p / 18, C2 = p - R2 * 18;
      int gr = gr0 - 1 + R2, gc = gc0 - 1 + C2;
      bool inb = (gr >= 0 && gr < 512 && gc >= 0 && gc < 512);
      _Float16* sb = hid + p * 64 + (quad & 1) * 4;
      const int csw = C2 & 7;
#pragma unroll
      for (int nt = 0; nt < 4; ++nt) {
        half4v w;
#pragma unroll
        for (int reg = 0; reg < 4; ++reg) {
          float v = inb ? fmaxf(acc1[nt][reg] + bAv[nt][reg], 0.f) : 0.f;
          w[reg] = (_Float16)v;
        }
        const int chunk = nt * 2 + (quad >> 1);
        *(half4v*)(sb + ((chunk ^ csw) * 8)) = w;
      }
    }
  }
  __syncthreads();
  mfma_body<1, 1, 1, false, float>(hid, BpB, b2b, op, 512, 512, gr0, gc0, tid);
}

extern "C" void kernel_launch(void* const* d_in, const int* in_sizes, int n_in,
                              void* d_out, int out_size, void* d_ws, size_t ws_size,
                              hipStream_t stream) {
  (void)in_sizes; (void)n_in; (void)out_size; (void)ws_size;
  const float* x   = (const float*)d_in[0];
  const float* g   = (const float*)d_in[1];
  const float* fWa = (const float*)d_in[2];
  const float* fba = (const float*)d_in[3];
  const float* fWb = (const float*)d_in[4];
  const float* fbb = (const float*)d_in[5];
  const float* fWc = (const float*)d_in[6];
  const float* fbc = (const float*)d_in[7];
  const float* W2a = (const float*)d_in[8];
  const float* b2a = (const float*)d_in[9];
  const float* W2b = (const float*)d_in[10];
  const float* b2b = (const float*)d_in[11];
  float* out = (float*)d_out;
  float* ws = (float*)d_ws;

  // carve (float units), total 42,009,088 floats = 168.04 MB
  float* Bp1F = ws;                     // 5120
  float* BpAF = Bp1F + 5120;            // 2048
  float* BpBF = BpAF + 2048;            // 4608
  float* BpbF = BpBF + 4608;            // 92160
  float* BpcF = BpbF + 92160;           // 138240
  float* s1F  = BpcF + 138240;          // 65536
  float* s2F  = s1F + 65536;            // 16384
  float* s3F  = s2F + 16384;            // 4096
  float* cat  = s3F + 4096;             // 2621440 (10 planes of 262144)
  float* h2F  = cat + 2621440;          // 39,059,456
  _Float16* s1 = (_Float16*)s1F;
  _Float16* s2 = (_Float16*)s2F;
  _Float16* s3 = (_Float16*)s3F;
  _Float16* h2 = (_Float16*)h2F;
  const half8* Bp1 = (const half8*)Bp1F;
  const half8* BpA = (const half8*)BpAF;
  const half8* BpB = (const half8*)BpBF;
  const half8* Bpb = (const half8*)BpbF;
  const half8* Bpc = (const half8*)BpcF;

  pack_all_kernel<<<1892, 256, 0, stream>>>(fWa, fWb, fWc, W2a, W2b,
                                            (_Float16*)Bp1F, (_Float16*)BpAF,
                                            (_Float16*)BpBF, (_Float16*)BpbF,
                                            (_Float16*)BpcF);
  down_all_kernel<<<672, 256, 0, stream>>>(x, s1, s2, s3);
  conv12_ms_kernel<<<4768, 256, 0, stream>>>(x, g, s1, s2, s3, Bp1, fba, Bpb, fbb, h2);
  conv3sd_ms_kernel<<<4768, 256, 0, stream>>>(h2, Bpc, fbc, x, g, s1, s2, s3, cat);
  tail_fused_kernel<<<dim3(32, 32, 2), 256, 0, stream>>>(cat, BpA, b2a, BpB, b2b, out);
}

// Round 13
// 412.419 us; speedup vs baseline: 1.3297x; 1.3297x over previous
//
#include <hip/hip_runtime.h>
#include <math.h>

typedef _Float16 half8 __attribute__((ext_vector_type(8)));
typedef _Float16 half4v __attribute__((ext_vector_type(4)));
typedef float f32x4 __attribute__((ext_vector_type(4)));

#define LOG2E 1.44269504f

// ---------------- merged prep: all 5 weight packs + 3 downsamples, one dispatch ------------
__device__ __forceinline__ void pack_generic(int rem, int NT, int COUT, float scale,
                                             const float* __restrict__ src,
                                             _Float16* __restrict__ dst) {
  int j = rem & 7, lane = (rem >> 3) & 63, rest = rem >> 9;
  int t = rest % NT, s = rest / NT;
  int oc = t * 16 + (lane & 15);
  int tap = s >> 1;
  int ic = (s & 1) * 32 + ((lane >> 4) & 3) * 8 + j;
  float v = (oc < COUT) ? src[((size_t)oc * 64 + ic) * 9 + tap] * scale : 0.f;
  dst[rem] = (_Float16)v;
}

__global__ void prep_all_kernel(const float* __restrict__ fWa, const float* __restrict__ fWb,
                                const float* __restrict__ fWc, const float* __restrict__ W2a,
                                const float* __restrict__ W2b, const float* __restrict__ x,
                                _Float16* __restrict__ Bp1, _Float16* __restrict__ BpA,
                                _Float16* __restrict__ BpB, _Float16* __restrict__ Bpb,
                                _Float16* __restrict__ Bpc,
                                _Float16* __restrict__ s1, _Float16* __restrict__ s2,
                                _Float16* __restrict__ s3) {
  int idx = blockIdx.x * blockDim.x + threadIdx.x;
  if (idx < 184320) {                       // Bpb: 5 scales x 18x4x512
    int sc = idx / 36864, rem = idx - sc * 36864;
    pack_generic(rem, 4, 64, 1.f, fWb + sc * 36864, Bpb + sc * 36864);
  } else if (idx < 460800) {                // Bpc: 5 scales x 18x6x512, prescaled by log2e
    int i2 = idx - 184320;
    int sc = i2 / 55296, rem = i2 - sc * 55296;
    pack_generic(rem, 6, 81, LOG2E, fWc + sc * 46656, Bpc + sc * 55296);
  } else if (idx < 471040) {                // Bp1: conv1, K=9 pad 32
    int i2 = idx - 460800;
    int sc = i2 >> 11, rem = i2 & 2047;
    int j = rem & 7, lane = (rem >> 3) & 63, nt = rem >> 9;
    int oc = nt * 16 + (lane & 15);
    int k = ((lane >> 4) & 3) * 8 + j;
    float v = (k < 9) ? fWa[sc * 576 + oc * 9 + k] : 0.f;
    Bp1[sc * 2048 + rem] = (_Float16)v;
  } else if (idx < 475136) {                // BpA: tail stage1, K=45 pad 64
    int rem = idx - 471040;
    int j = rem & 7, lane = (rem >> 3) & 63;
    int nt = (rem >> 9) & 3, s = rem >> 11;
    int oc = nt * 16 + (lane & 15);
    int k = s * 32 + ((lane >> 4) & 3) * 8 + j;
    float v = 0.f;
    if (k < 45) { int ic = k / 9, tap = k - ic * 9; v = W2a[(oc * 5 + ic) * 9 + tap]; }
    BpA[rem] = (_Float16)v;
  } else if (idx < 484352) {                // BpB: tail stage2 (COUT=1, NT=1)
    pack_generic(idx - 475136, 1, 1, 1.f, W2b, BpB);
  } else if (idx < 615424) {                // s1: 512->256, both batches
    int i2 = idx - 484352;
    int n = i2 >> 16, p = i2 & 65535, rr = p >> 8, cc = p & 255;
    s1[i2] = (_Float16)x[(size_t)n * 262144 + (size_t)(rr * 2) * 512 + cc * 2];
  } else if (idx < 648192) {                // s2: 512->128
    int i2 = idx - 615424;
    int n = i2 >> 14, p = i2 & 16383, rr = p >> 7, cc = p & 127;
    s2[i2] = (_Float16)x[(size_t)n * 262144 + (size_t)(rr * 4) * 512 + cc * 4];
  } else if (idx < 656384) {                // s3: 512->64
    int i2 = idx - 648192;
    int n = i2 >> 12, p = i2 & 4095, rr = p >> 6, cc = p & 63;
    s3[i2] = (_Float16)x[(size_t)n * 262144 + (size_t)(rr * 8) * 512 + cc * 8];
  }
}

// ---------------- block -> (scale, batch, tile) mapping, all 5 scales in one grid ----------
__device__ __forceinline__ void map_block(int bid, int& sc, int& n, int& bx, int& by,
                                          int& Hs, int& RS, int& h2off) {
  if (bid < 2048) { sc = 0; Hs = 512; RS = 1; h2off = 0;
    int t = bid; n = t >> 10; t &= 1023; by = t >> 5; bx = t & 31; }
  else if (bid < 4096) { sc = 4; Hs = 512; RS = 1; h2off = 33554432;
    int t = bid - 2048; n = t >> 10; t &= 1023; by = t >> 5; bx = t & 31; }
  else if (bid < 4608) { sc = 1; Hs = 256; RS = 2; h2off = 67108864;
    int t = bid - 4096; n = t >> 8; t &= 255; by = t >> 4; bx = t & 15; }
  else if (bid < 4736) { sc = 2; Hs = 128; RS = 4; h2off = 75497472;
    int t = bid - 4608; n = t >> 6; t &= 63; by = t >> 3; bx = t & 7; }
  else { sc = 3; Hs = 64; RS = 8; h2off = 77594624;
    int t = bid - 4736; n = t >> 4; t &= 15; by = t >> 2; bx = t & 3; }
}

__device__ __forceinline__ const void* pick_src(int sc, const float* x, const float* g,
                                                const _Float16* s1, const _Float16* s2,
                                                const _Float16* s3, int& sStr, bool& f16s) {
  if (sc == 0) { sStr = 262144; f16s = false; return x; }
  if (sc == 1) { sStr = 65536; f16s = true; return s1; }
  if (sc == 2) { sStr = 16384; f16s = true; return s2; }
  if (sc == 3) { sStr = 4096; f16s = true; return s3; }
  sStr = 262144; f16s = false; return g;
}

__device__ __forceinline__ float src_load(const void* p, bool f16s, size_t off) {
  return f16s ? (float)((const _Float16*)p)[off] : ((const float*)p)[off];
}

// ---------------- shared MFMA K-loop over 18x18x64 XOR-swizzled slab (r2-verified) ---------
// SWAP=false: D[px=quad*4+reg][ch=ln15]; SWAP=true: D[ch=quad*4+reg][px=ln15].
template <int NT, bool SWAP>
__device__ __forceinline__ void mfma_acc18(const _Float16* slab, const half8* __restrict__ Bp,
                                           f32x4 (&acc)[4][NT], int tid) {
  const int lane = tid & 63;
  const int wv = tid >> 6;
  const int quad = lane >> 4;
  const int ln15 = lane & 15;
  const f32x4 zz = {0.f, 0.f, 0.f, 0.f};
#pragma unroll
  for (int mt = 0; mt < 4; ++mt)
#pragma unroll
    for (int nt = 0; nt < NT; ++nt) acc[mt][nt] = zz;
#pragma unroll 1
  for (int s = 0; s < 18; ++s) {
    const int tap = s >> 1;
    const int dy = tap / 3;
    const int dx = tap - dy * 3;
    half8 bf[NT];
#pragma unroll
    for (int nt = 0; nt < NT; ++nt) bf[nt] = Bp[(s * NT + nt) * 64 + lane];
    const int C = dx + ln15;
    const int qsw = (((s & 1) * 4 + quad) ^ (C & 7));
    const _Float16* base = slab + C * 64 + qsw * 8;
    half8 af[4];
#pragma unroll
    for (int mt = 0; mt < 4; ++mt) {
      const int R = wv * 4 + mt + dy;
      af[mt] = *(const half8*)(base + R * (18 * 64));
    }
#pragma unroll
    for (int mt = 0; mt < 4; ++mt)
#pragma unroll
      for (int nt = 0; nt < NT; ++nt)
        acc[mt][nt] = SWAP
          ? __builtin_amdgcn_mfma_f32_16x16x32_f16(bf[nt], af[mt], acc[mt][nt], 0, 0, 0)
          : __builtin_amdgcn_mfma_f32_16x16x32_f16(af[mt], bf[nt], acc[mt][nt], 0, 0, 0);
  }
}

// K-loop + global-store epilogue (unswapped; px-major for write combining)
template <int NT, int COUT, int COUTP, bool RELU, typename OutT>
__device__ __forceinline__ void mfma_body(const _Float16* slab, const half8* __restrict__ Bp,
                                          const float* __restrict__ bias,
                                          OutT* __restrict__ out,
                                          int H, int W, int gr0, int gc0, int tid) {
  f32x4 acc[4][NT];
  mfma_acc18<NT, false>(slab, Bp, acc, tid);
  const int lane = tid & 63;
  const int wv = tid >> 6;
  const int quad = lane >> 4;
  const int ln15 = lane & 15;
  float bvv[NT];
#pragma unroll
  for (int nt = 0; nt < NT; ++nt) {
    const int oc = nt * 16 + ln15;
    bvv[nt] = (oc < COUT) ? bias[oc] : 0.f;
  }
#pragma unroll
  for (int mt = 0; mt < 4; ++mt) {
    const int gr = gr0 + wv * 4 + mt;
#pragma unroll
    for (int reg = 0; reg < 4; ++reg) {
      const int gc = gc0 + quad * 4 + reg;
#pragma unroll
      for (int nt = 0; nt < NT; ++nt) {
        const int oc = nt * 16 + ln15;
        float v = acc[mt][nt][reg] + bvv[nt];
        if (RELU) v = fmaxf(v, 0.f);
        if (oc < COUTP) out[((size_t)gr * W + gc) * COUTP + oc] = (OutT)v;
      }
    }
  }
}

// ---------------- all-scale fused conv1+conv2 (MFMA), single dispatch (r9/r10-proven) ------
__global__ __launch_bounds__(256)
void conv12_ms_kernel(const float* __restrict__ x, const float* __restrict__ g,
                      const _Float16* __restrict__ s1, const _Float16* __restrict__ s2,
                      const _Float16* __restrict__ s3,
                      const half8* __restrict__ Bp1b, const float* __restrict__ fba,
                      const half8* __restrict__ Bpbb, const float* __restrict__ fbb,
                      _Float16* __restrict__ h2) {
  __shared__ float xs[20 * 20];                         // first: gather clamps stay inside
  __shared__ __align__(16) _Float16 slab[18 * 18 * 64];
  int sc, n, bx, by, Hs, RS, h2off;
  map_block(blockIdx.x, sc, n, bx, by, Hs, RS, h2off);
  int sStr; bool f16s;
  const void* src = pick_src(sc, x, g, s1, s2, s3, sStr, f16s);
  _Float16* out = h2 + h2off + (size_t)n * Hs * Hs * 64;
  const half8* Bp1 = Bp1b + sc * 256;
  const half8* Bp = Bpbb + sc * 4608;
  const float* ba = fba + sc * 64;
  const float* bb = fbb + sc * 64;
  const int H = Hs, W = Hs;
  const int tid = threadIdx.x;
  const int gr0 = by * 16, gc0 = bx * 16;
  for (int i = tid; i < 400; i += 256) {
    int R = i / 20, C = i % 20;
    int gr = gr0 - 2 + R, gc = gc0 - 2 + C;
    xs[i] = (gr >= 0 && gr < H && gc >= 0 && gc < W)
                ? src_load(src, f16s, (size_t)n * sStr + (size_t)gr * W + gc) : 0.f;
  }
  __syncthreads();
  const int lane = tid & 63;
  const int wv = tid >> 6;
  const int quad = lane >> 4;
  const int ln15 = lane & 15;
  half8 bf1[4];
  float b1v[4][4];
#pragma unroll
  for (int nt = 0; nt < 4; ++nt) {
    bf1[nt] = Bp1[nt * 64 + lane];
#pragma unroll
    for (int reg = 0; reg < 4; ++reg) b1v[nt][reg] = ba[nt * 16 + quad * 4 + reg];
  }
  int off1[8];
  bool v1[8];
#pragma unroll
  for (int j = 0; j < 8; ++j) {
    int k = quad * 8 + j;
    v1[j] = (k < 9);
    off1[j] = v1[j] ? ((k / 3) * 20 + (k % 3)) : 0;
  }
  const f32x4 zz = {0.f, 0.f, 0.f, 0.f};
#pragma unroll 1
  for (int mt = wv; mt < 21; mt += 4) {
    int p = mt * 16 + ln15;
    int pcl = (p < 323) ? p : 323;
    int Rg = pcl / 18, Cg = pcl - Rg * 18;
    int base = Rg * 20 + Cg;
    half8 af;
#pragma unroll
    for (int j = 0; j < 8; ++j)
      af[j] = v1[j] ? (_Float16)xs[base + off1[j]] : (_Float16)0.f;
    f32x4 a1[4] = {zz, zz, zz, zz};
#pragma unroll
    for (int nt = 0; nt < 4; ++nt)
      a1[nt] = __builtin_amdgcn_mfma_f32_16x16x32_f16(bf1[nt], af, a1[nt], 0, 0, 0);
    if (p < 324) {
      int R2 = p / 18, C2 = p - R2 * 18;
      int gr = gr0 - 1 + R2, gc = gc0 - 1 + C2;
      bool inb = (gr >= 0 && gr < H && gc >= 0 && gc < W);
      _Float16* sb = slab + p * 64 + (quad & 1) * 4;
      const int csw = C2 & 7;
#pragma unroll
      for (int nt = 0; nt < 4; ++nt) {
        half4v w;
#pragma unroll
        for (int reg = 0; reg < 4; ++reg) {
          float v = inb ? fmaxf(a1[nt][reg] + b1v[nt][reg], 0.f) : 0.f;
          w[reg] = (_Float16)v;
        }
        const int chunk = nt * 2 + (quad >> 1);
        *(half4v*)(sb + ((chunk ^ csw) * 8)) = w;
      }
    }
  }
  __syncthreads();
  mfma_body<4, 64, 64, true, _Float16>(slab, Bp, bb, out, H, W, gr0, gc0, tid);
}

// ---------------- all-scale fused conv3 + softmax + dynconv + upsample (r10-proven) --------
// Split-K restage, stride-40 slab (25.9 KB); swapped MFMA epilogue; planar cat.
__global__ __launch_bounds__(256)
void conv3sd_ms_kernel(const _Float16* __restrict__ h2, const half8* __restrict__ Bpcb,
                       const float* __restrict__ fbc,
                       const float* __restrict__ x, const float* __restrict__ g,
                       const _Float16* __restrict__ s1, const _Float16* __restrict__ s2,
                       const _Float16* __restrict__ s3, float* __restrict__ cat) {
  __shared__ __align__(16) _Float16 slab[324 * 40];     // 25920 B
  __shared__ float xs[24 * 24];
  int sc, n, bx, by, Hs, RS, h2off;
  map_block(blockIdx.x, sc, n, bx, by, Hs, RS, h2off);
  int sStr; bool f16s;
  const void* src = pick_src(sc, x, g, s1, s2, s3, sStr, f16s);
  const _Float16* in = h2 + h2off + (size_t)n * Hs * Hs * 64;
  const half8* Bp = Bpcb + sc * 6912;
  const float* bias = fbc + sc * 81;
  float* catp = cat + (size_t)(sc * 2 + n) * 262144;
  const int H = Hs, W = Hs;
  const int tid = threadIdx.x;
  const int gr0 = by * 16, gc0 = bx * 16;
  const int lane = tid & 63;
  const int wv = tid >> 6;
  const int quad = lane >> 4;
  const int ln15 = lane & 15;
  for (int i = tid; i < 576; i += 256) {
    int R = i / 24, C = i % 24;
    int gr = gr0 - 4 + R, gc = gc0 - 4 + C;
    xs[i] = (gr >= 0 && gr < H && gc >= 0 && gc < W)
                ? src_load(src, f16s, (size_t)n * sStr + (size_t)gr * W + gc) : 0.f;
  }
  f32x4 acc[4][6];
  const f32x4 zz = {0.f, 0.f, 0.f, 0.f};
#pragma unroll
  for (int mt = 0; mt < 4; ++mt)
#pragma unroll
    for (int nt = 0; nt < 6; ++nt) acc[mt][nt] = zz;
#pragma unroll 1
  for (int h = 0; h < 2; ++h) {
    if (h) __syncthreads();                              // phase-A readers done
    for (int i = tid; i < 1296; i += 256) {              // 18*18 px x 4 chunks
      int chunk = i & 3, px = i >> 2;
      int R = px / 18, C = px - R * 18;
      int gr = gr0 - 1 + R, gc = gc0 - 1 + C;
      half8 v = {0, 0, 0, 0, 0, 0, 0, 0};
      if (gr >= 0 && gr < H && gc >= 0 && gc < W)
        v = *(const half8*)(in + ((size_t)gr * W + gc) * 64 + (h * 4 + chunk) * 8);
      *(half8*)(slab + px * 40 + chunk * 8) = v;
    }
    __syncthreads();
#pragma unroll 1
    for (int tap = 0; tap < 9; ++tap) {
      const int dy = tap / 3;
      const int dx = tap - dy * 3;
      half8 bf[6];
#pragma unroll
      for (int nt = 0; nt < 6; ++nt) bf[nt] = Bp[(((tap * 2 + h) * 6) + nt) * 64 + lane];
      const int C = dx + ln15;
      const _Float16* base = slab + C * 40 + quad * 8;
      half8 af[4];
#pragma unroll
      for (int mt = 0; mt < 4; ++mt) {
        const int R = wv * 4 + mt + dy;
        af[mt] = *(const half8*)(base + R * 720);        // 18*40
      }
#pragma unroll
      for (int mt = 0; mt < 4; ++mt)
#pragma unroll
        for (int nt = 0; nt < 6; ++nt)
          acc[mt][nt] = __builtin_amdgcn_mfma_f32_16x16x32_f16(bf[nt], af[mt], acc[mt][nt], 0, 0, 0);
    }
  }
  float bvv[6][4];
  int dyx[6][4];
  bool vv[6][4];
#pragma unroll
  for (int nt = 0; nt < 6; ++nt)
#pragma unroll
    for (int reg = 0; reg < 4; ++reg) {
      int ch = nt * 16 + quad * 4 + reg;
      bool ok = (ch < 81);
      vv[nt][reg] = ok;
      bvv[nt][reg] = ok ? bias[ch] * LOG2E : 0.f;
      int dy = ch / 9, dx = ch - dy * 9;
      dyx[nt][reg] = ok ? dy * 24 + dx : 0;
    }
  const int lrs = (RS == 2) ? 1 : ((RS == 4) ? 2 : 3);
#pragma unroll
  for (int mt = 0; mt < 4; ++mt) {
    const float* xb = xs + (wv * 4 + mt) * 24 + ln15;
    float sum = 0.f, y = 0.f;
#pragma unroll
    for (int nt = 0; nt < 6; ++nt)
#pragma unroll
      for (int reg = 0; reg < 4; ++reg) {
        if (vv[nt][reg]) {
          float e = exp2f(acc[mt][nt][reg] + bvv[nt][reg]);
          sum += e;
          y = fmaf(e, xb[dyx[nt][reg]], y);
        }
      }
    sum += __shfl_xor(sum, 16, 64);
    sum += __shfl_xor(sum, 32, 64);
    y += __shfl_xor(y, 16, 64);
    y += __shfl_xor(y, 32, 64);
    const float o = y / sum;
    const int gr = gr0 + wv * 4 + mt, gc = gc0 + ln15;
    if (RS == 1) {
      if (quad == 0) catp[(size_t)gr * 512 + gc] = o;
    } else {
      for (int t = quad; t < RS * RS; t += 4) {
        int a = t >> lrs, b = t & (RS - 1);
        catp[((size_t)(gr * RS + a)) * 512 + (gc * RS + b)] = o;
      }
    }
  }
}

// ---------------- fused tail: cat(5 planes) -> MFMA 5->64 relu (LDS) -> MFMA 64->1 ---------
__global__ __launch_bounds__(256)
void tail_fused_kernel(const float* __restrict__ cat,
                       const half8* __restrict__ BpA, const float* __restrict__ b2a,
                       const half8* __restrict__ BpB, const float* __restrict__ b2b,
                       float* __restrict__ out) {
  __shared__ float cs[20 * 20 * 5];                      // first: gather clamps stay inside
  __shared__ __align__(16) _Float16 hid[18 * 18 * 64];
  const int n = blockIdx.z;
  float* op = out + (size_t)n * (512 * 512);
  const int tid = threadIdx.x;
  const int gr0 = blockIdx.y * 16, gc0 = blockIdx.x * 16;
  for (int i = tid; i < 2000; i += 256) {
    int ic = i / 400, px = i - ic * 400;
    int R = px / 20, C = px - R * 20;
    int gr = gr0 - 2 + R, gc = gc0 - 2 + C;
    cs[px * 5 + ic] = (gr >= 0 && gr < 512 && gc >= 0 && gc < 512)
                ? cat[(size_t)(ic * 2 + n) * 262144 + (size_t)gr * 512 + gc] : 0.f;
  }
  __syncthreads();
  const int lane = tid & 63;
  const int wv = tid >> 6;
  const int quad = lane >> 4;
  const int ln15 = lane & 15;
  int goff[2][8];
  bool gok[2][8];
#pragma unroll
  for (int s = 0; s < 2; ++s)
#pragma unroll
    for (int j = 0; j < 8; ++j) {
      int k = s * 32 + quad * 8 + j;
      bool ok = (k < 45);
      int ic = k / 9;
      int tap = k - ic * 9;
      int dy = tap / 3, dx = tap - dy * 3;
      goff[s][j] = ok ? ((dy * 20 + dx) * 5 + ic) : 0;
      gok[s][j] = ok;
    }
  half8 bfA[2][4];
  float bAv[4][4];
#pragma unroll
  for (int s = 0; s < 2; ++s)
#pragma unroll
    for (int nt = 0; nt < 4; ++nt) bfA[s][nt] = BpA[(s * 4 + nt) * 64 + lane];
#pragma unroll
  for (int nt = 0; nt < 4; ++nt)
#pragma unroll
    for (int reg = 0; reg < 4; ++reg) bAv[nt][reg] = b2a[nt * 16 + quad * 4 + reg];
  const f32x4 zz = {0.f, 0.f, 0.f, 0.f};
#pragma unroll 1
  for (int mt = wv; mt < 21; mt += 4) {
    int p = mt * 16 + ln15;
    int pcl = (p < 323) ? p : 323;
    int base = (pcl / 18) * 100 + (pcl % 18) * 5;
    f32x4 acc1[4] = {zz, zz, zz, zz};
#pragma unroll
    for (int s = 0; s < 2; ++s) {
      half8 af;
#pragma unroll
      for (int j = 0; j < 8; ++j) {
        float a = gok[s][j] ? cs[base + goff[s][j]] : 0.f;
        af[j] = (_Float16)a;
      }
#pragma unroll
      for (int nt = 0; nt < 4; ++nt)
        acc1[nt] = __builtin_amdgcn_mfma_f32_16x16x32_f16(bfA[s][nt], af, acc1[nt], 0, 0, 0);
    }
    if (p < 324) {
      int R2 = p / 18, C2 = p - R2 * 18;
      int gr = gr0 - 1 + R2, gc = gc0 - 1 + C2;
      bool inb = (gr >= 0 && gr < 512 && gc >= 0 && gc < 512);
      _Float16* sb = hid + p * 64 + (quad & 1) * 4;
      const int csw = C2 & 7;
#pragma unroll
      for (int nt = 0; nt < 4; ++nt) {
        half4v w;
#pragma unroll
        for (int reg = 0; reg < 4; ++reg) {
          float v = inb ? fmaxf(acc1[nt][reg] + bAv[nt][reg], 0.f) : 0.f;
          w[reg] = (_Float16)v;
        }
        const int chunk = nt * 2 + (quad >> 1);
        *(half4v*)(sb + ((chunk ^ csw) * 8)) = w;
      }
    }
  }
  __syncthreads();
  mfma_body<1, 1, 1, false, float>(hid, BpB, b2b, op, 512, 512, gr0, gc0, tid);
}

extern "C" void kernel_launch(void* const* d_in, const int* in_sizes, int n_in,
                              void* d_out, int out_size, void* d_ws, size_t ws_size,
                              hipStream_t stream) {
  (void)in_sizes; (void)n_in; (void)out_size; (void)ws_size;
  const float* x   = (const float*)d_in[0];
  const float* g   = (const float*)d_in[1];
  const float* fWa = (const float*)d_in[2];
  const float* fba = (const float*)d_in[3];
  const float* fWb = (const float*)d_in[4];
  const float* fbb = (const float*)d_in[5];
  const float* fWc = (const float*)d_in[6];
  const float* fbc = (const float*)d_in[7];
  const float* W2a = (const float*)d_in[8];
  const float* b2a = (const float*)d_in[9];
  const float* W2b = (const float*)d_in[10];
  const float* b2b = (const float*)d_in[11];
  float* out = (float*)d_out;
  float* ws = (float*)d_ws;

  // carve (float units), total 42,009,088 floats = 168.04 MB
  float* Bp1F = ws;                     // 5120
  float* BpAF = Bp1F + 5120;            // 2048
  float* BpBF = BpAF + 2048;            // 4608
  float* BpbF = BpBF + 4608;            // 92160
  float* BpcF = BpbF + 92160;           // 138240
  float* s1F  = BpcF + 138240;          // 65536
  float* s2F  = s1F + 65536;            // 16384
  float* s3F  = s2F + 16384;            // 4096
  float* cat  = s3F + 4096;             // 2621440 (10 planes of 262144)
  float* h2F  = cat + 2621440;          // 39,059,456
  _Float16* s1 = (_Float16*)s1F;
  _Float16* s2 = (_Float16*)s2F;
  _Float16* s3 = (_Float16*)s3F;
  _Float16* h2 = (_Float16*)h2F;
  const half8* Bp1 = (const half8*)Bp1F;
  const half8* BpA = (const half8*)BpAF;
  const half8* BpB = (const half8*)BpBF;
  const half8* Bpb = (const half8*)BpbF;
  const half8* Bpc = (const half8*)BpcF;

  prep_all_kernel<<<2564, 256, 0, stream>>>(fWa, fWb, fWc, W2a, W2b, x,
                                            (_Float16*)Bp1F, (_Float16*)BpAF,
                                            (_Float16*)BpBF, (_Float16*)BpbF,
                                            (_Float16*)BpcF, s1, s2, s3);
  conv12_ms_kernel<<<4768, 256, 0, stream>>>(x, g, s1, s2, s3, Bp1, fba, Bpb, fbb, h2);
  conv3sd_ms_kernel<<<4768, 256, 0, stream>>>(h2, Bpc, fbc, x, g, s1, s2, s3, cat);
  tail_fused_kernel<<<dim3(32, 32, 2), 256, 0, stream>>>(cat, BpA, b2a, BpB, b2b, out);
}

// Round 14
// 410.974 us; speedup vs baseline: 1.3343x; 1.0035x over previous
//
#include <hip/hip_runtime.h>
#include <math.h>

typedef _Float16 half8 __attribute__((ext_vector_type(8)));
typedef _Float16 half4v __attribute__((ext_vector_type(4)));
typedef float f32x4 __attribute__((ext_vector_type(4)));

#define LOG2E 1.44269504f

// ---------------- merged prep: all 5 weight packs + 3 downsamples, one dispatch ------------
__device__ __forceinline__ void pack_generic(int rem, int NT, int COUT, float scale,
                                             const float* __restrict__ src,
                                             _Float16* __restrict__ dst) {
  int j = rem & 7, lane = (rem >> 3) & 63, rest = rem >> 9;
  int t = rest % NT, s = rest / NT;
  int oc = t * 16 + (lane & 15);
  int tap = s >> 1;
  int ic = (s & 1) * 32 + ((lane >> 4) & 3) * 8 + j;
  float v = (oc < COUT) ? src[((size_t)oc * 64 + ic) * 9 + tap] * scale : 0.f;
  dst[rem] = (_Float16)v;
}

__global__ void prep_all_kernel(const float* __restrict__ fWa, const float* __restrict__ fWb,
                                const float* __restrict__ fWc, const float* __restrict__ W2a,
                                const float* __restrict__ W2b, const float* __restrict__ x,
                                _Float16* __restrict__ Bp1, _Float16* __restrict__ BpA,
                                _Float16* __restrict__ BpB, _Float16* __restrict__ Bpb,
                                _Float16* __restrict__ Bpc,
                                _Float16* __restrict__ s1, _Float16* __restrict__ s2,
                                _Float16* __restrict__ s3) {
  int idx = blockIdx.x * blockDim.x + threadIdx.x;
  if (idx < 184320) {                       // Bpb: 5 scales x 18x4x512
    int sc = idx / 36864, rem = idx - sc * 36864;
    pack_generic(rem, 4, 64, 1.f, fWb + sc * 36864, Bpb + sc * 36864);
  } else if (idx < 460800) {                // Bpc: 5 scales x 18x6x512, prescaled by log2e
    int i2 = idx - 184320;
    int sc = i2 / 55296, rem = i2 - sc * 55296;
    pack_generic(rem, 6, 81, LOG2E, fWc + sc * 46656, Bpc + sc * 55296);
  } else if (idx < 471040) {                // Bp1: conv1, K=9 pad 32
    int i2 = idx - 460800;
    int sc = i2 >> 11, rem = i2 & 2047;
    int j = rem & 7, lane = (rem >> 3) & 63, nt = rem >> 9;
    int oc = nt * 16 + (lane & 15);
    int k = ((lane >> 4) & 3) * 8 + j;
    float v = (k < 9) ? fWa[sc * 576 + oc * 9 + k] : 0.f;
    Bp1[sc * 2048 + rem] = (_Float16)v;
  } else if (idx < 475136) {                // BpA: tail stage1, K=45 pad 64
    int rem = idx - 471040;
    int j = rem & 7, lane = (rem >> 3) & 63;
    int nt = (rem >> 9) & 3, s = rem >> 11;
    int oc = nt * 16 + (lane & 15);
    int k = s * 32 + ((lane >> 4) & 3) * 8 + j;
    float v = 0.f;
    if (k < 45) { int ic = k / 9, tap = k - ic * 9; v = W2a[(oc * 5 + ic) * 9 + tap]; }
    BpA[rem] = (_Float16)v;
  } else if (idx < 484352) {                // BpB: tail stage2 (COUT=1, NT=1)
    pack_generic(idx - 475136, 1, 1, 1.f, W2b, BpB);
  } else if (idx < 615424) {                // s1: 512->256, both batches
    int i2 = idx - 484352;
    int n = i2 >> 16, p = i2 & 65535, rr = p >> 8, cc = p & 255;
    s1[i2] = (_Float16)x[(size_t)n * 262144 + (size_t)(rr * 2) * 512 + cc * 2];
  } else if (idx < 648192) {                // s2: 512->128
    int i2 = idx - 615424;
    int n = i2 >> 14, p = i2 & 16383, rr = p >> 7, cc = p & 127;
    s2[i2] = (_Float16)x[(size_t)n * 262144 + (size_t)(rr * 4) * 512 + cc * 4];
  } else if (idx < 656384) {                // s3: 512->64
    int i2 = idx - 648192;
    int n = i2 >> 12, p = i2 & 4095, rr = p >> 6, cc = p & 63;
    s3[i2] = (_Float16)x[(size_t)n * 262144 + (size_t)(rr * 8) * 512 + cc * 8];
  }
}

// ---------------- block -> (scale, batch, tile) mapping, all 5 scales in one grid ----------
// XCD-aware swizzle: HW dispatches round-robin bid%8 -> XCD; remap so each XCD gets a
// contiguous 596-tile stretch (spatially adjacent tiles share h2/x halos in its L2).
__device__ __forceinline__ int xcd_swizzle(int bid) {
  return (bid & 7) * 596 + (bid >> 3);     // 4768 = 8 * 596
}

__device__ __forceinline__ void map_block(int bid, int& sc, int& n, int& bx, int& by,
                                          int& Hs, int& RS, int& h2off) {
  if (bid < 2048) { sc = 0; Hs = 512; RS = 1; h2off = 0;
    int t = bid; n = t >> 10; t &= 1023; by = t >> 5; bx = t & 31; }
  else if (bid < 4096) { sc = 4; Hs = 512; RS = 1; h2off = 33554432;
    int t = bid - 2048; n = t >> 10; t &= 1023; by = t >> 5; bx = t & 31; }
  else if (bid < 4608) { sc = 1; Hs = 256; RS = 2; h2off = 67108864;
    int t = bid - 4096; n = t >> 8; t &= 255; by = t >> 4; bx = t & 15; }
  else if (bid < 4736) { sc = 2; Hs = 128; RS = 4; h2off = 75497472;
    int t = bid - 4608; n = t >> 6; t &= 63; by = t >> 3; bx = t & 7; }
  else { sc = 3; Hs = 64; RS = 8; h2off = 77594624;
    int t = bid - 4736; n = t >> 4; t &= 15; by = t >> 2; bx = t & 3; }
}

__device__ __forceinline__ const void* pick_src(int sc, const float* x, const float* g,
                                                const _Float16* s1, const _Float16* s2,
                                                const _Float16* s3, int& sStr, bool& f16s) {
  if (sc == 0) { sStr = 262144; f16s = false; return x; }
  if (sc == 1) { sStr = 65536; f16s = true; return s1; }
  if (sc == 2) { sStr = 16384; f16s = true; return s2; }
  if (sc == 3) { sStr = 4096; f16s = true; return s3; }
  sStr = 262144; f16s = false; return g;
}

__device__ __forceinline__ float src_load(const void* p, bool f16s, size_t off) {
  return f16s ? (float)((const _Float16*)p)[off] : ((const float*)p)[off];
}

// ---------------- shared MFMA K-loop over 18x18x64 XOR-swizzled slab (r2-verified) ---------
// SWAP=false: D[px=quad*4+reg][ch=ln15]; SWAP=true: D[ch=quad*4+reg][px=ln15].
template <int NT, bool SWAP>
__device__ __forceinline__ void mfma_acc18(const _Float16* slab, const half8* __restrict__ Bp,
                                           f32x4 (&acc)[4][NT], int tid) {
  const int lane = tid & 63;
  const int wv = tid >> 6;
  const int quad = lane >> 4;
  const int ln15 = lane & 15;
  const f32x4 zz = {0.f, 0.f, 0.f, 0.f};
#pragma unroll
  for (int mt = 0; mt < 4; ++mt)
#pragma unroll
    for (int nt = 0; nt < NT; ++nt) acc[mt][nt] = zz;
#pragma unroll 1
  for (int s = 0; s < 18; ++s) {
    const int tap = s >> 1;
    const int dy = tap / 3;
    const int dx = tap - dy * 3;
    half8 bf[NT];
#pragma unroll
    for (int nt = 0; nt < NT; ++nt) bf[nt] = Bp[(s * NT + nt) * 64 + lane];
    const int C = dx + ln15;
    const int qsw = (((s & 1) * 4 + quad) ^ (C & 7));
    const _Float16* base = slab + C * 64 + qsw * 8;
    half8 af[4];
#pragma unroll
    for (int mt = 0; mt < 4; ++mt) {
      const int R = wv * 4 + mt + dy;
      af[mt] = *(const half8*)(base + R * (18 * 64));
    }
#pragma unroll
    for (int mt = 0; mt < 4; ++mt)
#pragma unroll
      for (int nt = 0; nt < NT; ++nt)
        acc[mt][nt] = SWAP
          ? __builtin_amdgcn_mfma_f32_16x16x32_f16(bf[nt], af[mt], acc[mt][nt], 0, 0, 0)
          : __builtin_amdgcn_mfma_f32_16x16x32_f16(af[mt], bf[nt], acc[mt][nt], 0, 0, 0);
  }
}

// K-loop + global-store epilogue (unswapped; px-major for write combining)
template <int NT, int COUT, int COUTP, bool RELU, typename OutT>
__device__ __forceinline__ void mfma_body(const _Float16* slab, const half8* __restrict__ Bp,
                                          const float* __restrict__ bias,
                                          OutT* __restrict__ out,
                                          int H, int W, int gr0, int gc0, int tid) {
  f32x4 acc[4][NT];
  mfma_acc18<NT, false>(slab, Bp, acc, tid);
  const int lane = tid & 63;
  const int wv = tid >> 6;
  const int quad = lane >> 4;
  const int ln15 = lane & 15;
  float bvv[NT];
#pragma unroll
  for (int nt = 0; nt < NT; ++nt) {
    const int oc = nt * 16 + ln15;
    bvv[nt] = (oc < COUT) ? bias[oc] : 0.f;
  }
#pragma unroll
  for (int mt = 0; mt < 4; ++mt) {
    const int gr = gr0 + wv * 4 + mt;
#pragma unroll
    for (int reg = 0; reg < 4; ++reg) {
      const int gc = gc0 + quad * 4 + reg;
#pragma unroll
      for (int nt = 0; nt < NT; ++nt) {
        const int oc = nt * 16 + ln15;
        float v = acc[mt][nt][reg] + bvv[nt];
        if (RELU) v = fmaxf(v, 0.f);
        if (oc < COUTP) out[((size_t)gr * W + gc) * COUTP + oc] = (OutT)v;
      }
    }
  }
}

// ---------------- all-scale fused conv1+conv2 (MFMA), single dispatch (r9/r10-proven) ------
__global__ __launch_bounds__(256)
void conv12_ms_kernel(const float* __restrict__ x, const float* __restrict__ g,
                      const _Float16* __restrict__ s1, const _Float16* __restrict__ s2,
                      const _Float16* __restrict__ s3,
                      const half8* __restrict__ Bp1b, const float* __restrict__ fba,
                      const half8* __restrict__ Bpbb, const float* __restrict__ fbb,
                      _Float16* __restrict__ h2) {
  __shared__ float xs[20 * 20];                         // first: gather clamps stay inside
  __shared__ __align__(16) _Float16 slab[18 * 18 * 64];
  int sc, n, bx, by, Hs, RS, h2off;
  map_block(xcd_swizzle(blockIdx.x), sc, n, bx, by, Hs, RS, h2off);
  int sStr; bool f16s;
  const void* src = pick_src(sc, x, g, s1, s2, s3, sStr, f16s);
  _Float16* out = h2 + h2off + (size_t)n * Hs * Hs * 64;
  const half8* Bp1 = Bp1b + sc * 256;
  const half8* Bp = Bpbb + sc * 4608;
  const float* ba = fba + sc * 64;
  const float* bb = fbb + sc * 64;
  const int H = Hs, W = Hs;
  const int tid = threadIdx.x;
  const int gr0 = by * 16, gc0 = bx * 16;
  for (int i = tid; i < 400; i += 256) {
    int R = i / 20, C = i % 20;
    int gr = gr0 - 2 + R, gc = gc0 - 2 + C;
    xs[i] = (gr >= 0 && gr < H && gc >= 0 && gc < W)
                ? src_load(src, f16s, (size_t)n * sStr + (size_t)gr * W + gc) : 0.f;
  }
  __syncthreads();
  const int lane = tid & 63;
  const int wv = tid >> 6;
  const int quad = lane >> 4;
  const int ln15 = lane & 15;
  half8 bf1[4];
  float b1v[4][4];
#pragma unroll
  for (int nt = 0; nt < 4; ++nt) {
    bf1[nt] = Bp1[nt * 64 + lane];
#pragma unroll
    for (int reg = 0; reg < 4; ++reg) b1v[nt][reg] = ba[nt * 16 + quad * 4 + reg];
  }
  int off1[8];
  bool v1[8];
#pragma unroll
  for (int j = 0; j < 8; ++j) {
    int k = quad * 8 + j;
    v1[j] = (k < 9);
    off1[j] = v1[j] ? ((k / 3) * 20 + (k % 3)) : 0;
  }
  const f32x4 zz = {0.f, 0.f, 0.f, 0.f};
#pragma unroll 1
  for (int mt = wv; mt < 21; mt += 4) {
    int p = mt * 16 + ln15;
    int pcl = (p < 323) ? p : 323;
    int Rg = pcl / 18, Cg = pcl - Rg * 18;
    int base = Rg * 20 + Cg;
    half8 af;
#pragma unroll
    for (int j = 0; j < 8; ++j)
      af[j] = v1[j] ? (_Float16)xs[base + off1[j]] : (_Float16)0.f;
    f32x4 a1[4] = {zz, zz, zz, zz};
#pragma unroll
    for (int nt = 0; nt < 4; ++nt)
      a1[nt] = __builtin_amdgcn_mfma_f32_16x16x32_f16(bf1[nt], af, a1[nt], 0, 0, 0);
    if (p < 324) {
      int R2 = p / 18, C2 = p - R2 * 18;
      int gr = gr0 - 1 + R2, gc = gc0 - 1 + C2;
      bool inb = (gr >= 0 && gr < H && gc >= 0 && gc < W);
      _Float16* sb = slab + p * 64 + (quad & 1) * 4;
      const int csw = C2 & 7;
#pragma unroll
      for (int nt = 0; nt < 4; ++nt) {
        half4v w;
#pragma unroll
        for (int reg = 0; reg < 4; ++reg) {
          float v = inb ? fmaxf(a1[nt][reg] + b1v[nt][reg], 0.f) : 0.f;
          w[reg] = (_Float16)v;
        }
        const int chunk = nt * 2 + (quad >> 1);
        *(half4v*)(sb + ((chunk ^ csw) * 8)) = w;
      }
    }
  }
  __syncthreads();
  mfma_body<4, 64, 64, true, _Float16>(slab, Bp, bb, out, H, W, gr0, gc0, tid);
}

// ---------------- all-scale fused conv3 + softmax + dynconv + upsample (r10-proven) --------
// Split-K restage, stride-40 slab (25.9 KB); swapped MFMA epilogue; planar cat.
__global__ __launch_bounds__(256)
void conv3sd_ms_kernel(const _Float16* __restrict__ h2, const half8* __restrict__ Bpcb,
                       const float* __restrict__ fbc,
                       const float* __restrict__ x, const float* __restrict__ g,
                       const _Float16* __restrict__ s1, const _Float16* __restrict__ s2,
                       const _Float16* __restrict__ s3, float* __restrict__ cat) {
  __shared__ __align__(16) _Float16 slab[324 * 40];     // 25920 B
  __shared__ float xs[24 * 24];
  int sc, n, bx, by, Hs, RS, h2off;
  map_block(xcd_swizzle(blockIdx.x), sc, n, bx, by, Hs, RS, h2off);
  int sStr; bool f16s;
  const void* src = pick_src(sc, x, g, s1, s2, s3, sStr, f16s);
  const _Float16* in = h2 + h2off + (size_t)n * Hs * Hs * 64;
  const half8* Bp = Bpcb + sc * 6912;
  const float* bias = fbc + sc * 81;
  float* catp = cat + (size_t)(sc * 2 + n) * 262144;
  const int H = Hs, W = Hs;
  const int tid = threadIdx.x;
  const int gr0 = by * 16, gc0 = bx * 16;
  const int lane = tid & 63;
  const int wv = tid >> 6;
  const int quad = lane >> 4;
  const int ln15 = lane & 15;
  for (int i = tid; i < 576; i += 256) {
    int R = i / 24, C = i % 24;
    int gr = gr0 - 4 + R, gc = gc0 - 4 + C;
    xs[i] = (gr >= 0 && gr < H && gc >= 0 && gc < W)
                ? src_load(src, f16s, (size_t)n * sStr + (size_t)gr * W + gc) : 0.f;
  }
  f32x4 acc[4][6];
  const f32x4 zz = {0.f, 0.f, 0.f, 0.f};
#pragma unroll
  for (int mt = 0; mt < 4; ++mt)
#pragma unroll
    for (int nt = 0; nt < 6; ++nt) acc[mt][nt] = zz;
#pragma unroll 1
  for (int h = 0; h < 2; ++h) {
    if (h) __syncthreads();                              // phase-A readers done
    for (int i = tid; i < 1296; i += 256) {              // 18*18 px x 4 chunks
      int chunk = i & 3, px = i >> 2;
      int R = px / 18, C = px - R * 18;
      int gr = gr0 - 1 + R, gc = gc0 - 1 + C;
      half8 v = {0, 0, 0, 0, 0, 0, 0, 0};
      if (gr >= 0 && gr < H && gc >= 0 && gc < W)
        v = *(const half8*)(in + ((size_t)gr * W + gc) * 64 + (h * 4 + chunk) * 8);
      *(half8*)(slab + px * 40 + chunk * 8) = v;
    }
    __syncthreads();
#pragma unroll 1
    for (int tap = 0; tap < 9; ++tap) {
      const int dy = tap / 3;
      const int dx = tap - dy * 3;
      half8 bf[6];
#pragma unroll
      for (int nt = 0; nt < 6; ++nt) bf[nt] = Bp[(((tap * 2 + h) * 6) + nt) * 64 + lane];
      const int C = dx + ln15;
      const _Float16* base = slab + C * 40 + quad * 8;
      half8 af[4];
#pragma unroll
      for (int mt = 0; mt < 4; ++mt) {
        const int R = wv * 4 + mt + dy;
        af[mt] = *(const half8*)(base + R * 720);        // 18*40
      }
#pragma unroll
      for (int mt = 0; mt < 4; ++mt)
#pragma unroll
        for (int nt = 0; nt < 6; ++nt)
          acc[mt][nt] = __builtin_amdgcn_mfma_f32_16x16x32_f16(bf[nt], af[mt], acc[mt][nt], 0, 0, 0);
    }
  }
  float bvv[6][4];
  int dyx[6][4];
  bool vv[6][4];
#pragma unroll
  for (int nt = 0; nt < 6; ++nt)
#pragma unroll
    for (int reg = 0; reg < 4; ++reg) {
      int ch = nt * 16 + quad * 4 + reg;
      bool ok = (ch < 81);
      vv[nt][reg] = ok;
      bvv[nt][reg] = ok ? bias[ch] * LOG2E : 0.f;
      int dy = ch / 9, dx = ch - dy * 9;
      dyx[nt][reg] = ok ? dy * 24 + dx : 0;
    }
  const int lrs = (RS == 2) ? 1 : ((RS == 4) ? 2 : 3);
#pragma unroll
  for (int mt = 0; mt < 4; ++mt) {
    const float* xb = xs + (wv * 4 + mt) * 24 + ln15;
    float sum = 0.f, y = 0.f;
#pragma unroll
    for (int nt = 0; nt < 6; ++nt)
#pragma unroll
      for (int reg = 0; reg < 4; ++reg) {
        if (vv[nt][reg]) {
          float e = exp2f(acc[mt][nt][reg] + bvv[nt][reg]);
          sum += e;
          y = fmaf(e, xb[dyx[nt][reg]], y);
        }
      }
    sum += __shfl_xor(sum, 16, 64);
    sum += __shfl_xor(sum, 32, 64);
    y += __shfl_xor(y, 16, 64);
    y += __shfl_xor(y, 32, 64);
    const float o = y / sum;
    const int gr = gr0 + wv * 4 + mt, gc = gc0 + ln15;
    if (RS == 1) {
      if (quad == 0) catp[(size_t)gr * 512 + gc] = o;
    } else {
      for (int t = quad; t < RS * RS; t += 4) {
        int a = t >> lrs, b = t & (RS - 1);
        catp[((size_t)(gr * RS + a)) * 512 + (gc * RS + b)] = o;
      }
    }
  }
}

// ---------------- fused tail: cat(5 planes) -> MFMA 5->64 relu (LDS) -> MFMA 64->1 ---------
__global__ __launch_bounds__(256)
void tail_fused_kernel(const float* __restrict__ cat,
                       const half8* __restrict__ BpA, const float* __restrict__ b2a,
                       const half8* __restrict__ BpB, const float* __restrict__ b2b,
                       float* __restrict__ out) {
  __shared__ float cs[20 * 20 * 5];                      // first: gather clamps stay inside
  __shared__ __align__(16) _Float16 hid[18 * 18 * 64];
  const int n = blockIdx.z;
  float* op = out + (size_t)n * (512 * 512);
  const int tid = threadIdx.x;
  const int gr0 = blockIdx.y * 16, gc0 = blockIdx.x * 16;
  for (int i = tid; i < 2000; i += 256) {
    int ic = i / 400, px = i - ic * 400;
    int R = px / 20, C = px - R * 20;
    int gr = gr0 - 2 + R, gc = gc0 - 2 + C;
    cs[px * 5 + ic] = (gr >= 0 && gr < 512 && gc >= 0 && gc < 512)
                ? cat[(size_t)(ic * 2 + n) * 262144 + (size_t)gr * 512 + gc] : 0.f;
  }
  __syncthreads();
  const int lane = tid & 63;
  const int wv = tid >> 6;
  const int quad = lane >> 4;
  const int ln15 = lane & 15;
  int goff[2][8];
  bool gok[2][8];
#pragma unroll
  for (int s = 0; s < 2; ++s)
#pragma unroll
    for (int j = 0; j < 8; ++j) {
      int k = s * 32 + quad * 8 + j;
      bool ok = (k < 45);
      int ic = k / 9;
      int tap = k - ic * 9;
      int dy = tap / 3, dx = tap - dy * 3;
      goff[s][j] = ok ? ((dy * 20 + dx) * 5 + ic) : 0;
      gok[s][j] = ok;
    }
  half8 bfA[2][4];
  float bAv[4][4];
#pragma unroll
  for (int s = 0; s < 2; ++s)
#pragma unroll
    for (int nt = 0; nt < 4; ++nt) bfA[s][nt] = BpA[(s * 4 + nt) * 64 + lane];
#pragma unroll
  for (int nt = 0; nt < 4; ++nt)
#pragma unroll
    for (int reg = 0; reg < 4; ++reg) bAv[nt][reg] = b2a[nt * 16 + quad * 4 + reg];
  const f32x4 zz = {0.f, 0.f, 0.f, 0.f};
#pragma unroll 1
  for (int mt = wv; mt < 21; mt += 4) {
    int p = mt * 16 + ln15;
    int pcl = (p < 323) ? p : 323;
    int base = (pcl / 18) * 100 + (pcl % 18) * 5;
    f32x4 acc1[4] = {zz, zz, zz, zz};
#pragma unroll
    for (int s = 0; s < 2; ++s) {
      half8 af;
#pragma unroll
      for (int j = 0; j < 8; ++j) {
        float a = gok[s][j] ? cs[base + goff[s][j]] : 0.f;
        af[j] = (_Float16)a;
      }
#pragma unroll
      for (int nt = 0; nt < 4; ++nt)
        acc1[nt] = __builtin_amdgcn_mfma_f32_16x16x32_f16(bfA[s][nt], af, acc1[nt], 0, 0, 0);
    }
    if (p < 324) {
      int R2 = p / 18, C2 = p - R2 * 18;
      int gr = gr0 - 1 + R2, gc = gc0 - 1 + C2;
      bool inb = (gr >= 0 && gr < 512 && gc >= 0 && gc < 512);
      _Float16* sb = hid + p * 64 + (quad & 1) * 4;
      const int csw = C2 & 7;
#pragma unroll
      for (int nt = 0; nt < 4; ++nt) {
        half4v w;
#pragma unroll
        for (int reg = 0; reg < 4; ++reg) {
          float v = inb ? fmaxf(acc1[nt][reg] + bAv[nt][reg], 0.f) : 0.f;
          w[reg] = (_Float16)v;
        }
        const int chunk = nt * 2 + (quad >> 1);
        *(half4v*)(sb + ((chunk ^ csw) * 8)) = w;
      }
    }
  }
  __syncthreads();
  mfma_body<1, 1, 1, false, float>(hid, BpB, b2b, op, 512, 512, gr0, gc0, tid);
}

extern "C" void kernel_launch(void* const* d_in, const int* in_sizes, int n_in,
                              void* d_out, int out_size, void* d_ws, size_t ws_size,
                              hipStream_t stream) {
  (void)in_sizes; (void)n_in; (void)out_size; (void)ws_size;
  const float* x   = (const float*)d_in[0];
  const float* g   = (const float*)d_in[1];
  const float* fWa = (const float*)d_in[2];
  const float* fba = (const float*)d_in[3];
  const float* fWb = (const float*)d_in[4];
  const float* fbb = (const float*)d_in[5];
  const float* fWc = (const float*)d_in[6];
  const float* fbc = (const float*)d_in[7];
  const float* W2a = (const float*)d_in[8];
  const float* b2a = (const float*)d_in[9];
  const float* W2b = (const float*)d_in[10];
  const float* b2b = (const float*)d_in[11];
  float* out = (float*)d_out;
  float* ws = (float*)d_ws;

  // carve (float units), total 42,009,088 floats = 168.04 MB
  float* Bp1F = ws;                     // 5120
  float* BpAF = Bp1F + 5120;            // 2048
  float* BpBF = BpAF + 2048;            // 4608
  float* BpbF = BpBF + 4608;            // 92160
  float* BpcF = BpbF + 92160;           // 138240
  float* s1F  = BpcF + 138240;          // 65536
  float* s2F  = s1F + 65536;            // 16384
  float* s3F  = s2F + 16384;            // 4096
  float* cat  = s3F + 4096;             // 2621440 (10 planes of 262144)
  float* h2F  = cat + 2621440;          // 39,059,456
  _Float16* s1 = (_Float16*)s1F;
  _Float16* s2 = (_Float16*)s2F;
  _Float16* s3 = (_Float16*)s3F;
  _Float16* h2 = (_Float16*)h2F;
  const half8* Bp1 = (const half8*)Bp1F;
  const half8* BpA = (const half8*)BpAF;
  const half8* BpB = (const half8*)BpBF;
  const half8* Bpb = (const half8*)BpbF;
  const half8* Bpc = (const half8*)BpcF;

  prep_all_kernel<<<2564, 256, 0, stream>>>(fWa, fWb, fWc, W2a, W2b, x,
                                            (_Float16*)Bp1F, (_Float16*)BpAF,
                                            (_Float16*)BpBF, (_Float16*)BpbF,
                                            (_Float16*)BpcF, s1, s2, s3);
  conv12_ms_kernel<<<4768, 256, 0, stream>>>(x, g, s1, s2, s3, Bp1, fba, Bpb, fbb, h2);
  conv3sd_ms_kernel<<<4768, 256, 0, stream>>>(h2, Bpc, fbc, x, g, s1, s2, s3, cat);
  tail_fused_kernel<<<dim3(32, 32, 2), 256, 0, stream>>>(cat, BpA, b2a, BpB, b2b, out);
}

// Round 15
// 392.331 us; speedup vs baseline: 1.3977x; 1.0475x over previous
//
#include <hip/hip_runtime.h>
#include <math.h>

typedef _Float16 half8 __attribute__((ext_vector_type(8)));
typedef _Float16 half4v __attribute__((ext_vector_type(4)));
typedef float f32x4 __attribute__((ext_vector_type(4)));

#define LOG2E 1.44269504f

// ---------------- merged prep: all 5 weight packs + 3 downsamples, one dispatch ------------
__device__ __forceinline__ void pack_generic(int rem, int NT, int COUT, float scale,
                                             const float* __restrict__ src,
                                             _Float16* __restrict__ dst) {
  int j = rem & 7, lane = (rem >> 3) & 63, rest = rem >> 9;
  int t = rest % NT, s = rest / NT;
  int oc = t * 16 + (lane & 15);
  int tap = s >> 1;
  int ic = (s & 1) * 32 + ((lane >> 4) & 3) * 8 + j;
  float v = (oc < COUT) ? src[((size_t)oc * 64 + ic) * 9 + tap] * scale : 0.f;
  dst[rem] = (_Float16)v;
}

__global__ void prep_all_kernel(const float* __restrict__ fWa, const float* __restrict__ fWb,
                                const float* __restrict__ fWc, const float* __restrict__ W2a,
                                const float* __restrict__ W2b, const float* __restrict__ x,
                                _Float16* __restrict__ Bp1, _Float16* __restrict__ BpA,
                                _Float16* __restrict__ BpB, _Float16* __restrict__ Bpb,
                                _Float16* __restrict__ Bpc,
                                _Float16* __restrict__ s1, _Float16* __restrict__ s2,
                                _Float16* __restrict__ s3) {
  int idx = blockIdx.x * blockDim.x + threadIdx.x;
  if (idx < 184320) {                       // Bpb: 5 scales x 18x4x512
    int sc = idx / 36864, rem = idx - sc * 36864;
    pack_generic(rem, 4, 64, 1.f, fWb + sc * 36864, Bpb + sc * 36864);
  } else if (idx < 460800) {                // Bpc: 5 scales x 18x6x512, prescaled by log2e
    int i2 = idx - 184320;
    int sc = i2 / 55296, rem = i2 - sc * 55296;
    pack_generic(rem, 6, 81, LOG2E, fWc + sc * 46656, Bpc + sc * 55296);
  } else if (idx < 471040) {                // Bp1: conv1, K=9 pad 32
    int i2 = idx - 460800;
    int sc = i2 >> 11, rem = i2 & 2047;
    int j = rem & 7, lane = (rem >> 3) & 63, nt = rem >> 9;
    int oc = nt * 16 + (lane & 15);
    int k = ((lane >> 4) & 3) * 8 + j;
    float v = (k < 9) ? fWa[sc * 576 + oc * 9 + k] : 0.f;
    Bp1[sc * 2048 + rem] = (_Float16)v;
  } else if (idx < 475136) {                // BpA: tail stage1, K=45 pad 64
    int rem = idx - 471040;
    int j = rem & 7, lane = (rem >> 3) & 63;
    int nt = (rem >> 9) & 3, s = rem >> 11;
    int oc = nt * 16 + (lane & 15);
    int k = s * 32 + ((lane >> 4) & 3) * 8 + j;
    float v = 0.f;
    if (k < 45) { int ic = k / 9, tap = k - ic * 9; v = W2a[(oc * 5 + ic) * 9 + tap]; }
    BpA[rem] = (_Float16)v;
  } else if (idx < 484352) {                // BpB: tail stage2 (COUT=1, NT=1)
    pack_generic(idx - 475136, 1, 1, 1.f, W2b, BpB);
  } else if (idx < 615424) {                // s1: 512->256, both batches
    int i2 = idx - 484352;
    int n = i2 >> 16, p = i2 & 65535, rr = p >> 8, cc = p & 255;
    s1[i2] = (_Float16)x[(size_t)n * 262144 + (size_t)(rr * 2) * 512 + cc * 2];
  } else if (idx < 648192) {                // s2: 512->128
    int i2 = idx - 615424;
    int n = i2 >> 14, p = i2 & 16383, rr = p >> 7, cc = p & 127;
    s2[i2] = (_Float16)x[(size_t)n * 262144 + (size_t)(rr * 4) * 512 + cc * 4];
  } else if (idx < 656384) {                // s3: 512->64
    int i2 = idx - 648192;
    int n = i2 >> 12, p = i2 & 4095, rr = p >> 6, cc = p & 63;
    s3[i2] = (_Float16)x[(size_t)n * 262144 + (size_t)(rr * 8) * 512 + cc * 8];
  }
}

// ---------------- block -> (scale, batch, tile) mapping, all 5 scales in one grid ----------
// XCD-aware swizzle (r14): each XCD gets a contiguous 596-tile stretch.
__device__ __forceinline__ int xcd_swizzle(int bid) {
  return (bid & 7) * 596 + (bid >> 3);     // 4768 = 8 * 596
}

__device__ __forceinline__ void map_block(int bid, int& sc, int& n, int& bx, int& by,
                                          int& Hs, int& RS, int& h2off) {
  if (bid < 2048) { sc = 0; Hs = 512; RS = 1; h2off = 0;
    int t = bid; n = t >> 10; t &= 1023; by = t >> 5; bx = t & 31; }
  else if (bid < 4096) { sc = 4; Hs = 512; RS = 1; h2off = 33554432;
    int t = bid - 2048; n = t >> 10; t &= 1023; by = t >> 5; bx = t & 31; }
  else if (bid < 4608) { sc = 1; Hs = 256; RS = 2; h2off = 67108864;
    int t = bid - 4096; n = t >> 8; t &= 255; by = t >> 4; bx = t & 15; }
  else if (bid < 4736) { sc = 2; Hs = 128; RS = 4; h2off = 75497472;
    int t = bid - 4608; n = t >> 6; t &= 63; by = t >> 3; bx = t & 7; }
  else { sc = 3; Hs = 64; RS = 8; h2off = 77594624;
    int t = bid - 4736; n = t >> 4; t &= 15; by = t >> 2; bx = t & 3; }
}

__device__ __forceinline__ const void* pick_src(int sc, const float* x, const float* g,
                                                const _Float16* s1, const _Float16* s2,
                                                const _Float16* s3, int& sStr, bool& f16s) {
  if (sc == 0) { sStr = 262144; f16s = false; return x; }
  if (sc == 1) { sStr = 65536; f16s = true; return s1; }
  if (sc == 2) { sStr = 16384; f16s = true; return s2; }
  if (sc == 3) { sStr = 4096; f16s = true; return s3; }
  sStr = 262144; f16s = false; return g;
}

__device__ __forceinline__ float src_load(const void* p, bool f16s, size_t off) {
  return f16s ? (float)((const _Float16*)p)[off] : ((const float*)p)[off];
}

// ---------------- shared MFMA K-loop over 18x18x64 XOR-swizzled slab (r2-verified) ---------
// r15: B-fragment loads software-pipelined with register ping-pong (no copies) so tap t+1's
// global loads overlap tap t's LDS reads + MFMAs.
template <int NT, bool SWAP>
__device__ __forceinline__ void mfma_acc18(const _Float16* slab, const half8* __restrict__ Bp,
                                           f32x4 (&acc)[4][NT], int tid) {
  const int lane = tid & 63;
  const int wv = tid >> 6;
  const int quad = lane >> 4;
  const int ln15 = lane & 15;
  const f32x4 zz = {0.f, 0.f, 0.f, 0.f};
#pragma unroll
  for (int mt = 0; mt < 4; ++mt)
#pragma unroll
    for (int nt = 0; nt < NT; ++nt) acc[mt][nt] = zz;
  auto step = [&](int s, half8 (&bf)[NT]) {
    const int tap = s >> 1;
    const int dy = tap / 3;
    const int dx = tap - dy * 3;
    const int C = dx + ln15;
    const int qsw = (((s & 1) * 4 + quad) ^ (C & 7));
    const _Float16* base = slab + C * 64 + qsw * 8;
    half8 af[4];
#pragma unroll
    for (int mt = 0; mt < 4; ++mt)
      af[mt] = *(const half8*)(base + (wv * 4 + mt + dy) * (18 * 64));
#pragma unroll
    for (int mt = 0; mt < 4; ++mt)
#pragma unroll
      for (int nt = 0; nt < NT; ++nt)
        acc[mt][nt] = SWAP
          ? __builtin_amdgcn_mfma_f32_16x16x32_f16(bf[nt], af[mt], acc[mt][nt], 0, 0, 0)
          : __builtin_amdgcn_mfma_f32_16x16x32_f16(af[mt], bf[nt], acc[mt][nt], 0, 0, 0);
  };
  half8 bA[NT], bB[NT];
#pragma unroll
  for (int nt = 0; nt < NT; ++nt) bA[nt] = Bp[nt * 64 + lane];            // s=0
#pragma unroll 1
  for (int i = 0; i < 9; ++i) {
    const int s0 = 2 * i, s1 = 2 * i + 1;
    const int s2 = (s1 + 1 < 18) ? s1 + 1 : 17;                           // clamp (redundant)
#pragma unroll
    for (int nt = 0; nt < NT; ++nt) bB[nt] = Bp[(s1 * NT + nt) * 64 + lane];
    step(s0, bA);
#pragma unroll
    for (int nt = 0; nt < NT; ++nt) bA[nt] = Bp[(s2 * NT + nt) * 64 + lane];
    step(s1, bB);
  }
}

// K-loop + global-store epilogue (unswapped; px-major for write combining)
template <int NT, int COUT, int COUTP, bool RELU, typename OutT>
__device__ __forceinline__ void mfma_body(const _Float16* slab, const half8* __restrict__ Bp,
                                          const float* __restrict__ bias,
                                          OutT* __restrict__ out,
                                          int H, int W, int gr0, int gc0, int tid) {
  f32x4 acc[4][NT];
  mfma_acc18<NT, false>(slab, Bp, acc, tid);
  const int lane = tid & 63;
  const int wv = tid >> 6;
  const int quad = lane >> 4;
  const int ln15 = lane & 15;
  float bvv[NT];
#pragma unroll
  for (int nt = 0; nt < NT; ++nt) {
    const int oc = nt * 16 + ln15;
    bvv[nt] = (oc < COUT) ? bias[oc] : 0.f;
  }
#pragma unroll
  for (int mt = 0; mt < 4; ++mt) {
    const int gr = gr0 + wv * 4 + mt;
#pragma unroll
    for (int reg = 0; reg < 4; ++reg) {
      const int gc = gc0 + quad * 4 + reg;
#pragma unroll
      for (int nt = 0; nt < NT; ++nt) {
        const int oc = nt * 16 + ln15;
        float v = acc[mt][nt][reg] + bvv[nt];
        if (RELU) v = fmaxf(v, 0.f);
        if (oc < COUTP) out[((size_t)gr * W + gc) * COUTP + oc] = (OutT)v;
      }
    }
  }
}

// ---------------- all-scale fused conv1+conv2 (MFMA), single dispatch (r9/r10-proven) ------
__global__ __launch_bounds__(256)
void conv12_ms_kernel(const float* __restrict__ x, const float* __restrict__ g,
                      const _Float16* __restrict__ s1, const _Float16* __restrict__ s2,
                      const _Float16* __restrict__ s3,
                      const half8* __restrict__ Bp1b, const float* __restrict__ fba,
                      const half8* __restrict__ Bpbb, const float* __restrict__ fbb,
                      _Float16* __restrict__ h2) {
  __shared__ float xs[20 * 20];                         // first: gather clamps stay inside
  __shared__ __align__(16) _Float16 slab[18 * 18 * 64];
  int sc, n, bx, by, Hs, RS, h2off;
  map_block(xcd_swizzle(blockIdx.x), sc, n, bx, by, Hs, RS, h2off);
  int sStr; bool f16s;
  const void* src = pick_src(sc, x, g, s1, s2, s3, sStr, f16s);
  _Float16* out = h2 + h2off + (size_t)n * Hs * Hs * 64;
  const half8* Bp1 = Bp1b + sc * 256;
  const half8* Bp = Bpbb + sc * 4608;
  const float* ba = fba + sc * 64;
  const float* bb = fbb + sc * 64;
  const int H = Hs, W = Hs;
  const int tid = threadIdx.x;
  const int gr0 = by * 16, gc0 = bx * 16;
  for (int i = tid; i < 400; i += 256) {
    int R = i / 20, C = i % 20;
    int gr = gr0 - 2 + R, gc = gc0 - 2 + C;
    xs[i] = (gr >= 0 && gr < H && gc >= 0 && gc < W)
                ? src_load(src, f16s, (size_t)n * sStr + (size_t)gr * W + gc) : 0.f;
  }
  __syncthreads();
  const int lane = tid & 63;
  const int wv = tid >> 6;
  const int quad = lane >> 4;
  const int ln15 = lane & 15;
  half8 bf1[4];
  float b1v[4][4];
#pragma unroll
  for (int nt = 0; nt < 4; ++nt) {
    bf1[nt] = Bp1[nt * 64 + lane];
#pragma unroll
    for (int reg = 0; reg < 4; ++reg) b1v[nt][reg] = ba[nt * 16 + quad * 4 + reg];
  }
  int off1[8];
  bool v1[8];
#pragma unroll
  for (int j = 0; j < 8; ++j) {
    int k = quad * 8 + j;
    v1[j] = (k < 9);
    off1[j] = v1[j] ? ((k / 3) * 20 + (k % 3)) : 0;
  }
  const f32x4 zz = {0.f, 0.f, 0.f, 0.f};
#pragma unroll 1
  for (int mt = wv; mt < 21; mt += 4) {
    int p = mt * 16 + ln15;
    int pcl = (p < 323) ? p : 323;
    int Rg = pcl / 18, Cg = pcl - Rg * 18;
    int base = Rg * 20 + Cg;
    half8 af;
#pragma unroll
    for (int j = 0; j < 8; ++j)
      af[j] = v1[j] ? (_Float16)xs[base + off1[j]] : (_Float16)0.f;
    f32x4 a1[4] = {zz, zz, zz, zz};
#pragma unroll
    for (int nt = 0; nt < 4; ++nt)
      a1[nt] = __builtin_amdgcn_mfma_f32_16x16x32_f16(bf1[nt], af, a1[nt], 0, 0, 0);
    if (p < 324) {
      int R2 = p / 18, C2 = p - R2 * 18;
      int gr = gr0 - 1 + R2, gc = gc0 - 1 + C2;
      bool inb = (gr >= 0 && gr < H && gc >= 0 && gc < W);
      _Float16* sb = slab + p * 64 + (quad & 1) * 4;
      const int csw = C2 & 7;
#pragma unroll
      for (int nt = 0; nt < 4; ++nt) {
        half4v w;
#pragma unroll
        for (int reg = 0; reg < 4; ++reg) {
          float v = inb ? fmaxf(a1[nt][reg] + b1v[nt][reg], 0.f) : 0.f;
          w[reg] = (_Float16)v;
        }
        const int chunk = nt * 2 + (quad >> 1);
        *(half4v*)(sb + ((chunk ^ csw) * 8)) = w;
      }
    }
  }
  __syncthreads();
  mfma_body<4, 64, 64, true, _Float16>(slab, Bp, bb, out, H, W, gr0, gc0, tid);
}

// ---------------- all-scale fused conv3 + softmax + dynconv + upsample ---------------------
// r10 structure (split-K stride-40 slab, swapped MFMA, planar cat) + r15 bf ping-pong.
__global__ __launch_bounds__(256)
void conv3sd_ms_kernel(const _Float16* __restrict__ h2, const half8* __restrict__ Bpcb,
                       const float* __restrict__ fbc,
                       const float* __restrict__ x, const float* __restrict__ g,
                       const _Float16* __restrict__ s1, const _Float16* __restrict__ s2,
                       const _Float16* __restrict__ s3, float* __restrict__ cat) {
  __shared__ __align__(16) _Float16 slab[324 * 40];     // 25920 B
  __shared__ float xs[24 * 24];
  int sc, n, bx, by, Hs, RS, h2off;
  map_block(xcd_swizzle(blockIdx.x), sc, n, bx, by, Hs, RS, h2off);
  int sStr; bool f16s;
  const void* src = pick_src(sc, x, g, s1, s2, s3, sStr, f16s);
  const _Float16* in = h2 + h2off + (size_t)n * Hs * Hs * 64;
  const half8* Bp = Bpcb + sc * 6912;
  const float* bias = fbc + sc * 81;
  float* catp = cat + (size_t)(sc * 2 + n) * 262144;
  const int H = Hs, W = Hs;
  const int tid = threadIdx.x;
  const int gr0 = by * 16, gc0 = bx * 16;
  const int lane = tid & 63;
  const int wv = tid >> 6;
  const int quad = lane >> 4;
  const int ln15 = lane & 15;
  for (int i = tid; i < 576; i += 256) {
    int R = i / 24, C = i % 24;
    int gr = gr0 - 4 + R, gc = gc0 - 4 + C;
    xs[i] = (gr >= 0 && gr < H && gc >= 0 && gc < W)
                ? src_load(src, f16s, (size_t)n * sStr + (size_t)gr * W + gc) : 0.f;
  }
  f32x4 acc[4][6];
  const f32x4 zz = {0.f, 0.f, 0.f, 0.f};
#pragma unroll
  for (int mt = 0; mt < 4; ++mt)
#pragma unroll
    for (int nt = 0; nt < 6; ++nt) acc[mt][nt] = zz;
#pragma unroll 1
  for (int h = 0; h < 2; ++h) {
    if (h) __syncthreads();                              // phase-A readers done
    for (int i = tid; i < 1296; i += 256) {              // 18*18 px x 4 chunks
      int chunk = i & 3, px = i >> 2;
      int R = px / 18, C = px - R * 18;
      int gr = gr0 - 1 + R, gc = gc0 - 1 + C;
      half8 v = {0, 0, 0, 0, 0, 0, 0, 0};
      if (gr >= 0 && gr < H && gc >= 0 && gc < W)
        v = *(const half8*)(in + ((size_t)gr * W + gc) * 64 + (h * 4 + chunk) * 8);
      *(half8*)(slab + px * 40 + chunk * 8) = v;
    }
    __syncthreads();
    auto ctap = [&](int tap, half8 (&bf)[6]) {
      const int dy = tap / 3;
      const int dx = tap - dy * 3;
      const int C = dx + ln15;
      const _Float16* base = slab + C * 40 + quad * 8;
      half8 af[4];
#pragma unroll
      for (int mt = 0; mt < 4; ++mt)
        af[mt] = *(const half8*)(base + (wv * 4 + mt + dy) * 720);  // 18*40
#pragma unroll
      for (int mt = 0; mt < 4; ++mt)
#pragma unroll
        for (int nt = 0; nt < 6; ++nt)
          acc[mt][nt] = __builtin_amdgcn_mfma_f32_16x16x32_f16(bf[nt], af[mt], acc[mt][nt], 0, 0, 0);
    };
    half8 bA[6], bB[6];
#pragma unroll
    for (int nt = 0; nt < 6; ++nt) bA[nt] = Bp[(h * 6 + nt) * 64 + lane];      // tap 0
#pragma unroll 1
    for (int i = 0; i < 4; ++i) {
      const int t1 = 2 * i + 1, t2 = 2 * i + 2;
#pragma unroll
      for (int nt = 0; nt < 6; ++nt) bB[nt] = Bp[(((t1 * 2 + h) * 6) + nt) * 64 + lane];
      ctap(2 * i, bA);
#pragma unroll
      for (int nt = 0; nt < 6; ++nt) bA[nt] = Bp[(((t2 * 2 + h) * 6) + nt) * 64 + lane];
      ctap(t1, bB);
    }
    ctap(8, bA);
  }
  float bvv[6][4];
  int dyx[6][4];
  bool vv[6][4];
#pragma unroll
  for (int nt = 0; nt < 6; ++nt)
#pragma unroll
    for (int reg = 0; reg < 4; ++reg) {
      int ch = nt * 16 + quad * 4 + reg;
      bool ok = (ch < 81);
      vv[nt][reg] = ok;
      bvv[nt][reg] = ok ? bias[ch] * LOG2E : 0.f;
      int dy = ch / 9, dx = ch - dy * 9;
      dyx[nt][reg] = ok ? dy * 24 + dx : 0;
    }
  const int lrs = (RS == 2) ? 1 : ((RS == 4) ? 2 : 3);
#pragma unroll
  for (int mt = 0; mt < 4; ++mt) {
    const float* xb = xs + (wv * 4 + mt) * 24 + ln15;
    float sum = 0.f, y = 0.f;
#pragma unroll
    for (int nt = 0; nt < 6; ++nt)
#pragma unroll
      for (int reg = 0; reg < 4; ++reg) {
        if (vv[nt][reg]) {
          float e = exp2f(acc[mt][nt][reg] + bvv[nt][reg]);
          sum += e;
          y = fmaf(e, xb[dyx[nt][reg]], y);
        }
      }
    sum += __shfl_xor(sum, 16, 64);
    sum += __shfl_xor(sum, 32, 64);
    y += __shfl_xor(y, 16, 64);
    y += __shfl_xor(y, 32, 64);
    const float o = y / sum;
    const int gr = gr0 + wv * 4 + mt, gc = gc0 + ln15;
    if (RS == 1) {
      if (quad == 0) catp[(size_t)gr * 512 + gc] = o;
    } else {
      for (int t = quad; t < RS * RS; t += 4) {
        int a = t >> lrs, b = t & (RS - 1);
        catp[((size_t)(gr * RS + a)) * 512 + (gc * RS + b)] = o;
      }
    }
  }
}

// ---------------- fused tail: cat(5 planes) -> MFMA 5->64 relu (LDS) -> MFMA 64->1 ---------
__global__ __launch_bounds__(256)
void tail_fused_kernel(const float* __restrict__ cat,
                       const half8* __restrict__ BpA, const float* __restrict__ b2a,
                       const half8* __restrict__ BpB, const float* __restrict__ b2b,
                       float* __restrict__ out) {
  __shared__ float cs[20 * 20 * 5];                      // first: gather clamps stay inside
  __shared__ __align__(16) _Float16 hid[18 * 18 * 64];
  const int n = blockIdx.z;
  float* op = out + (size_t)n * (512 * 512);
  const int tid = threadIdx.x;
  const int gr0 = blockIdx.y * 16, gc0 = blockIdx.x * 16;
  for (int i = tid; i < 2000; i += 256) {
    int ic = i / 400, px = i - ic * 400;
    int R = px / 20, C = px - R * 20;
    int gr = gr0 - 2 + R, gc = gc0 - 2 + C;
    cs[px * 5 + ic] = (gr >= 0 && gr < 512 && gc >= 0 && gc < 512)
                ? cat[(size_t)(ic * 2 + n) * 262144 + (size_t)gr * 512 + gc] : 0.f;
  }
  __syncthreads();
  const int lane = tid & 63;
  const int wv = tid >> 6;
  const int quad = lane >> 4;
  const int ln15 = lane & 15;
  int goff[2][8];
  bool gok[2][8];
#pragma unroll
  for (int s = 0; s < 2; ++s)
#pragma unroll
    for (int j = 0; j < 8; ++j) {
      int k = s * 32 + quad * 8 + j;
      bool ok = (k < 45);
      int ic = k / 9;
      int tap = k - ic * 9;
      int dy = tap / 3, dx = tap - dy * 3;
      goff[s][j] = ok ? ((dy * 20 + dx) * 5 + ic) : 0;
      gok[s][j] = ok;
    }
  half8 bfA[2][4];
  float bAv[4][4];
#pragma unroll
  for (int s = 0; s < 2; ++s)
#pragma unroll
    for (int nt = 0; nt < 4; ++nt) bfA[s][nt] = BpA[(s * 4 + nt) * 64 + lane];
#pragma unroll
  for (int nt = 0; nt < 4; ++nt)
#pragma unroll
    for (int reg = 0; reg < 4; ++reg) bAv[nt][reg] = b2a[nt * 16 + quad * 4 + reg];
  const f32x4 zz = {0.f, 0.f, 0.f, 0.f};
#pragma unroll 1
  for (int mt = wv; mt < 21; mt += 4) {
    int p = mt * 16 + ln15;
    int pcl = (p < 323) ? p : 323;
    int base = (pcl / 18) * 100 + (pcl % 18) * 5;
    f32x4 acc1[4] = {zz, zz, zz, zz};
#pragma unroll
    for (int s = 0; s < 2; ++s) {
      half8 af;
#pragma unroll
      for (int j = 0; j < 8; ++j) {
        float a = gok[s][j] ? cs[base + goff[s][j]] : 0.f;
        af[j] = (_Float16)a;
      }
#pragma unroll
      for (int nt = 0; nt < 4; ++nt)
        acc1[nt] = __builtin_amdgcn_mfma_f32_16x16x32_f16(bfA[s][nt], af, acc1[nt], 0, 0, 0);
    }
    if (p < 324) {
      int R2 = p / 18, C2 = p - R2 * 18;
      int gr = gr0 - 1 + R2, gc = gc0 - 1 + C2;
      bool inb = (gr >= 0 && gr < 512 && gc >= 0 && gc < 512);
      _Float16* sb = hid + p * 64 + (quad & 1) * 4;
      const int csw = C2 & 7;
#pragma unroll
      for (int nt = 0; nt < 4; ++nt) {
        half4v w;
#pragma unroll
        for (int reg = 0; reg < 4; ++reg) {
          float v = inb ? fmaxf(acc1[nt][reg] + bAv[nt][reg], 0.f) : 0.f;
          w[reg] = (_Float16)v;
        }
        const int chunk = nt * 2 + (quad >> 1);
        *(half4v*)(sb + ((chunk ^ csw) * 8)) = w;
      }
    }
  }
  __syncthreads();
  mfma_body<1, 1, 1, false, float>(hid, BpB, b2b, op, 512, 512, gr0, gc0, tid);
}

extern "C" void kernel_launch(void* const* d_in, const int* in_sizes, int n_in,
                              void* d_out, int out_size, void* d_ws, size_t ws_size,
                              hipStream_t stream) {
  (void)in_sizes; (void)n_in; (void)out_size; (void)ws_size;
  const float* x   = (const float*)d_in[0];
  const float* g   = (const float*)d_in[1];
  const float* fWa = (const float*)d_in[2];
  const float* fba = (const float*)d_in[3];
  const float* fWb = (const float*)d_in[4];
  const float* fbb = (const float*)d_in[5];
  const float* fWc = (const float*)d_in[6];
  const float* fbc = (const float*)d_in[7];
  const float* W2a = (const float*)d_in[8];
  const float* b2a = (const float*)d_in[9];
  const float* W2b = (const float*)d_in[10];
  const float* b2b = (const float*)d_in[11];
  float* out = (float*)d_out;
  float* ws = (float*)d_ws;

  // carve (float units), total 42,009,088 floats = 168.04 MB
  float* Bp1F = ws;                     // 5120
  float* BpAF = Bp1F + 5120;            // 2048
  float* BpBF = BpAF + 2048;            // 4608
  float* BpbF = BpBF + 4608;            // 92160
  float* BpcF = BpbF + 92160;           // 138240
  float* s1F  = BpcF + 138240;          // 65536
  float* s2F  = s1F + 65536;            // 16384
  float* s3F  = s2F + 16384;            // 4096
  float* cat  = s3F + 4096;             // 2621440 (10 planes of 262144)
  float* h2F  = cat + 2621440;          // 39,059,456
  _Float16* s1 = (_Float16*)s1F;
  _Float16* s2 = (_Float16*)s2F;
  _Float16* s3 = (_Float16*)s3F;
  _Float16* h2 = (_Float16*)h2F;
  const half8* Bp1 = (const half8*)Bp1F;
  const half8* BpA = (const half8*)BpAF;
  const half8* BpB = (const half8*)BpBF;
  const half8* Bpb = (const half8*)BpbF;
  const half8* Bpc = (const half8*)BpcF;

  prep_all_kernel<<<2564, 256, 0, stream>>>(fWa, fWb, fWc, W2a, W2b, x,
                                            (_Float16*)Bp1F, (_Float16*)BpAF,
                                            (_Float16*)BpBF, (_Float16*)BpbF,
                                            (_Float16*)BpcF, s1, s2, s3);
  conv12_ms_kernel<<<4768, 256, 0, stream>>>(x, g, s1, s2, s3, Bp1, fba, Bpb, fbb, h2);
  conv3sd_ms_kernel<<<4768, 256, 0, stream>>>(h2, Bpc, fbc, x, g, s1, s2, s3, cat);
  tail_fused_kernel<<<dim3(32, 32, 2), 256, 0, stream>>>(cat, BpA, b2a, BpB, b2b, out);
}